// Round 4
// baseline (441.981 us; speedup 1.0000x reference)
//
#include <hip/hip_runtime.h>
#include <float.h>

#define BATCH 16
#define NPTS  2048
#define NS0   256
#define NS1   128
#define KK    32
#define EPSV  1e-5f
#define MROWS 32768.0f   // BATCH*NPTS
#define M0F   131072.0f  // BATCH*NS0*KK
#define M1F   65536.0f   // BATCH*NS1*KK

// exact numpy-order squared distance: ((dx*dx + dy*dy) + dz*dz), no FMA contraction
__device__ __forceinline__ float sqdist(float ax,float ay,float az,float bx,float by,float bz){
  float dx=__fsub_rn(ax,bx), dy=__fsub_rn(ay,by), dz=__fsub_rn(az,bz);
  return __fadd_rn(__fadd_rn(__fmul_rn(dx,dx),__fmul_rn(dy,dy)),__fmul_rn(dz,dz));
}

// ---- native f32/u32 DPP ladders (cheap wave64 reduce; winner broadcast via readlane 63)
template<int CTRL,int RM>
__device__ __forceinline__ float dpp_fmax_s(float x){
  int t = __builtin_amdgcn_update_dpp((int)0xFF800000, __float_as_int(x), CTRL, RM, 0xf, false);
  return fmaxf(x, __int_as_float(t));
}
template<int CTRL,int RM>
__device__ __forceinline__ unsigned dpp_umin_s(unsigned x){
  unsigned t = (unsigned)__builtin_amdgcn_update_dpp(-1, (int)x, CTRL, RM, 0xf, false);
  return t<x ? t : x;
}
// argmax over (v,idx): max value, tie -> lowest idx (matches np.argmax first-occurrence)
// FROZEN with fps_body v4 — do not replace with packed u64 ladder (r1: +34us regression).
__device__ __forceinline__ void wave_argmax_f32(float v, unsigned idx, float& mall, int& sel){
  float m=v;
  m=dpp_fmax_s<0x111,0xf>(m); m=dpp_fmax_s<0x112,0xf>(m); m=dpp_fmax_s<0x114,0xf>(m);
  m=dpp_fmax_s<0x118,0xf>(m); m=dpp_fmax_s<0x142,0xa>(m); m=dpp_fmax_s<0x143,0xc>(m);
  mall = __int_as_float(__builtin_amdgcn_readlane(__float_as_int(m),63));
  unsigned c = (v==mall)? idx : 0xFFFFFFFFu;
  c=dpp_umin_s<0x111,0xf>(c); c=dpp_umin_s<0x112,0xf>(c); c=dpp_umin_s<0x114,0xf>(c);
  c=dpp_umin_s<0x118,0xf>(c); c=dpp_umin_s<0x142,0xa>(c); c=dpp_umin_s<0x143,0xc>(c);
  sel = (int)(unsigned)__builtin_amdgcn_readlane((int)c,63);
}

// ---- packed u64 argmin (kept: neutral-to-positive in KNN tournaments, r1/r2) ----
template<int CTRL,int RM>
__device__ __forceinline__ unsigned long long dpp_umin64_s(unsigned long long x){
  unsigned tlo=(unsigned)__builtin_amdgcn_update_dpp(-1,(int)(unsigned)x,        CTRL,RM,0xf,false);
  unsigned thi=(unsigned)__builtin_amdgcn_update_dpp(-1,(int)(unsigned)(x>>32), CTRL,RM,0xf,false);
  unsigned long long t=((unsigned long long)thi<<32)|tlo;
  return t<x ? t : x;
}
__device__ __forceinline__ int wave_argmin_f32(float v, unsigned idx){
  unsigned long long k = ((unsigned long long)__float_as_uint(v)<<32) | (unsigned long long)idx;
  k=dpp_umin64_s<0x111,0xf>(k); k=dpp_umin64_s<0x112,0xf>(k); k=dpp_umin64_s<0x114,0xf>(k);
  k=dpp_umin64_s<0x118,0xf>(k); k=dpp_umin64_s<0x142,0xa>(k); k=dpp_umin64_s<0x143,0xc>(k);
  return (int)(unsigned)__builtin_amdgcn_readlane((int)(unsigned)k,63);
}

// ---- wave-local sync: orders LDS writes->reads within a converged wave ----
__device__ __forceinline__ void wave_sync(){
  asm volatile("s_waitcnt lgkmcnt(0)" ::: "memory");
  __builtin_amdgcn_sched_barrier(0);
}

// ---- relaxed agent-scope poll, BOUNDED (protocol bug -> visible wrong result, not a hang).
// All data guarded by this flag is read via agent-scope ATOMIC loads (coherent point),
// so no consumer-side cache invalidate is needed (the r3 bug: guarded PLAIN reads).
__device__ __forceinline__ void wait_ge(int* flag, int want){
  for(int t=0; t<(1<<20); ++t){
    if(__hip_atomic_load(flag, __ATOMIC_RELAXED, __HIP_MEMORY_SCOPE_AGENT) >= want) break;
    __builtin_amdgcn_s_sleep(2);
  }
  asm volatile("" ::: "memory");
}

// ================= device bodies =================

// embed1 v3: 64 points/block, LDS-staged coalesced t1 writes + FUSED BN1 stats
__device__ void embed1_body(int bid, const float* __restrict__ x, const float* __restrict__ w1,
                            float* __restrict__ coords, float* __restrict__ t1,
                            float* __restrict__ accS, float* __restrict__ accQ){
  __shared__ float w[192];
  __shared__ float xs[3][64];
  __shared__ float fin[64][65];
  __shared__ float ls[64], lq[64];
  int tid = threadIdx.x;
  if (tid < 192) w[tid] = w1[tid];
  int base = bid*64;
  int b = base / NPTS, n0 = base % NPTS;
  if (tid < 192){
    int ch = tid>>6, i = tid&63;
    xs[ch][i] = x[((size_t)b*3+ch)*NPTS + n0 + i];
  } else {
    int t = tid - 192;
    ls[t]=0.f; lq[t]=0.f;
  }
  __syncthreads();
  if (tid < 64){
    coords[(size_t)(base+tid)*3+0]=xs[0][tid];
    coords[(size_t)(base+tid)*3+1]=xs[1][tid];
    coords[(size_t)(base+tid)*3+2]=xs[2][tid];
  }
  int p = tid>>2, c0 = (tid&3)<<4;
  float cx=xs[0][p], cy=xs[1][p], cz=xs[2][p];
  #pragma unroll
  for(int j=0;j<16;j++){
    int c = c0+j;
    fin[p][c] = cx*w[c*3+0] + cy*w[c*3+1] + cz*w[c*3+2];
  }
  __syncthreads();
  float s_=0.f, q_=0.f;
  for(int i=tid;i<4096;i+=256){
    int pp=i>>6, c=i&63;
    float v = fin[pp][c];
    t1[(size_t)base*64 + i] = v;
    s_+=v; q_+=v*v;
  }
  atomicAdd(&ls[tid&63], s_);
  atomicAdd(&lq[tid&63], q_);
  __syncthreads();
  if(tid<64){ atomicAdd(accS+tid, ls[tid]); atomicAdd(accQ+tid, lq[tid]); }
}

__device__ void wt_body(int gid, const float* __restrict__ w0, float* __restrict__ wt0,
                        const float* __restrict__ w1, float* __restrict__ wt1){
  if(gid < 128*128){
    int o = gid % 128, c = gid / 128;
    wt0[gid] = w0[o*128 + c];
  } else {
    int g2 = gid - 128*128;
    if(g2 >= 256*256) return;
    int o = g2 % 256, c = g2 / 256;
    wt1[g2] = w1[o*256 + c];
  }
}

// embed2 + fused BN2 stats (now its own kernel: its outputs become prior-kernel data
// for the mega's consumers -> plain loads are safe, no within-kernel flag needed)
__device__ void embed2_body(int bid, const float* __restrict__ t1, const float* __restrict__ w2,
                            const float* __restrict__ accS, const float* __restrict__ accQ,
                            const float* __restrict__ g1, const float* __restrict__ b1,
                            float* __restrict__ t2,
                            float* __restrict__ acc2S, float* __restrict__ acc2Q,
                            float* ls, float* lq, char* smem){
  float (*fin)[64] = (float(*)[64])smem;
  float* sm = (float*)smem + 4096;
  float* sr = sm+64; float* sg = sr+64; float* sb = sg+64;
  int tid = threadIdx.x;
  if (tid<64){
    float S=accS[tid], Q=accQ[tid];
    float m = S/MROWS, v = Q/MROWS - m*m; if(v<0.f) v=0.f;
    sm[tid]=m; sr[tid]=rsqrtf(v+EPSV); sg[tid]=g1[tid]; sb[tid]=b1[tid];
    ls[tid]=0.f; lq[tid]=0.f;
  }
  __syncthreads();
  int base = bid*64;
  for(int i=tid;i<4096;i+=256){
    int p=i>>6, c=i&63;
    float v = t1[(size_t)(base+p)*64 + c];
    v = (v - sm[c])*sr[c]*sg[c] + sb[c];
    fin[p][c] = v>0.f ? v : 0.f;
  }
  __syncthreads();
  int o = tid & 63, p0 = tid>>6;
  float acc[16];
  #pragma unroll
  for(int i=0;i<16;i++) acc[i]=0.f;
  for(int cc=0; cc<64; cc+=4){
    float4 wv = *(const float4*)(w2 + o*64 + cc);
    #pragma unroll
    for(int i=0;i<16;i++){
      float4 f4 = *(const float4*)&fin[p0 + i*4][cc];
      acc[i] += f4.x*wv.x + f4.y*wv.y + f4.z*wv.z + f4.w*wv.w;
    }
  }
  float s=0.f,q=0.f;
  #pragma unroll
  for(int i=0;i<16;i++){
    float v = acc[i];
    t2[(size_t)(base+p0+i*4)*64 + o] = v;
    s+=v; q+=v*v;
  }
  atomicAdd(&ls[o], s);
  atomicAdd(&lq[o], q);
  __syncthreads();
  if(tid<64){ atomicAdd(acc2S+tid, ls[tid]); atomicAdd(acc2Q+tid, lq[tid]); }
}

// multi-wave FPS v4 (FROZEN loop: measured 124-127us) + tid0-only incremental publish.
// Publish = plain stores of center idx/xyz, then RELEASE atomic store to prog every 32
// iters (release covers tid0's prior stores: waitcnt + L2 writeback before the flag).
template<int P, int S, int T>
__device__ void fps_body(int b, const float* __restrict__ x, int* __restrict__ outIdx,
                         float* __restrict__ outXyz, char* smem, int* prog){
  constexpr int PPT = P/T;
  constexpr int NW  = T/64;
  float* sx=(float*)smem; float* sy=sx+P; float* sz=sy+P;
  int* sidx=(int*)(sz+P);
  unsigned long long* rv64=(unsigned long long*)(sidx+S);
  int tid = threadIdx.x;
  const float* xb = x + (size_t)b*3*P;
  float px[PPT], py[PPT], pz[PPT], dist[PPT];
  #pragma unroll
  for(int i=0;i<PPT;i++){
    int n = i*T + tid;
    float X=xb[n], Y=xb[P+n], Z=xb[2*P+n];
    px[i]=X; py[i]=Y; pz[i]=Z; dist[i]=1e10f;
    sx[n]=X; sy[n]=Y; sz[n]=Z;
  }
  __syncthreads();
  int cur = 0;
  float cx=sx[0], cy=sy[0], cz=sz[0];
  for(int s=0;s<S;s++){
    if(tid==0){
      sidx[s]=cur;
      size_t o = (size_t)b*S + s;
      outIdx[o]=cur;
      outXyz[o*3+0]=cx; outXyz[o*3+1]=cy; outXyz[o*3+2]=cz;
      if((s&31)==31)
        __hip_atomic_store(prog+b, s+1, __ATOMIC_RELEASE, __HIP_MEMORY_SCOPE_AGENT);
    }
    if(s==S-1) break;
    float bv=-FLT_MAX; int bi=0;
    #pragma unroll
    for(int i=0;i<PPT;i++){
      float d = sqdist(px[i],py[i],pz[i],cx,cy,cz);
      float nd = fminf(dist[i], d);
      dist[i]=nd;
      int n = i*T + tid;
      if(nd>bv){ bv=nd; bi=n; }
    }
    float mall; int sel;
    wave_argmax_f32(bv,(unsigned)bi,mall,sel);
    int sl = s & 1;
    if((tid&63)==0) rv64[sl*NW+(tid>>6)] = ((unsigned long long)__float_as_uint(mall)<<32)|(unsigned)(~sel);
    __syncthreads();
    unsigned long long wk = rv64[sl*NW];
    #pragma unroll
    for(int w=1;w<NW;w++){ unsigned long long t = rv64[sl*NW+w]; if(t>wk) wk=t; }
    cur = (int)(~(unsigned)wk);
    cx=sx[cur]; cy=sy[cur]; cz=sz[cur];
  }
  __syncthreads();
  for(int i=tid; i<S; i+=T){
    int id = sidx[i];
    outIdx[b*S+i] = id;
    outXyz[((size_t)b*S+i)*3+0] = sx[id];
    outXyz[((size_t)b*S+i)*3+1] = sy[id];
    outXyz[((size_t)b*S+i)*3+2] = sz[id];
  }
  __syncthreads();   // all waves' stores drained to L2 at barrier (compiler vmcnt(0))
  if(tid==0)
    __hip_atomic_store(prog+b, S, __ATOMIC_RELEASE, __HIP_MEMORY_SCOPE_AGENT);
}

// single-wave FPS, wave-local; xyz0 staged via agent-scope ATOMIC loads (within-kernel
// cross-XCD data: plain loads could hit stale per-XCD L2 lines from a prior replay).
template<int P, int S>
__device__ void fps1_wave(int b, float* __restrict__ pts, int* __restrict__ outIdx,
                          float* __restrict__ outXyz, char* smem){
  constexpr int PPT = P/64;
  float4* sp = (float4*)smem;
  int* sidx = (int*)(smem + P*sizeof(float4));
  int lane = threadIdx.x & 63;
  float* p = pts + (size_t)b*P*3;
  float px[PPT], py[PPT], pz[PPT], dist[PPT];
  #pragma unroll
  for(int i=0;i<PPT;i++){
    int n = i*64 + lane;
    float X=__hip_atomic_load(p+n*3+0, __ATOMIC_RELAXED, __HIP_MEMORY_SCOPE_AGENT);
    float Y=__hip_atomic_load(p+n*3+1, __ATOMIC_RELAXED, __HIP_MEMORY_SCOPE_AGENT);
    float Z=__hip_atomic_load(p+n*3+2, __ATOMIC_RELAXED, __HIP_MEMORY_SCOPE_AGENT);
    px[i]=X; py[i]=Y; pz[i]=Z; dist[i]=1e10f;
    sp[n] = make_float4(X,Y,Z,0.f);
  }
  wave_sync();
  int cur = 0;
  float cx=sp[0].x, cy=sp[0].y, cz=sp[0].z;
  for(int s=0;s<S;s++){
    if(lane==0) sidx[s]=cur;
    if(s==S-1) break;
    float bv=-FLT_MAX; int bi=0;
    #pragma unroll
    for(int i=0;i<PPT;i++){
      float d = sqdist(px[i],py[i],pz[i],cx,cy,cz);
      float nd = fminf(dist[i], d);
      dist[i]=nd;
      int n = i*64 + lane;
      if(nd>bv){ bv=nd; bi=n; }
    }
    float mall; int sel;
    wave_argmax_f32(bv,(unsigned)bi,mall,sel);
    cur = sel;
    float4 cp = sp[cur];
    cx=cp.x; cy=cp.y; cz=cp.z;
  }
  wave_sync();
  for(int i=lane; i<S; i+=64){
    int id = sidx[i];
    float4 cp = sp[id];
    outIdx[b*S+i] = id;
    outXyz[((size_t)b*S+i)*3+0] = cp.x;
    outXyz[((size_t)b*S+i)*3+1] = cp.y;
    outXyz[((size_t)b*S+i)*3+2] = cp.z;
  }
}

// KNN tournament v3: per-lane top-2 cache + consumed bitmask, one wave
template<int P>
__device__ void knn_compute(const float* __restrict__ p, float qx, float qy, float qz,
                            int* outRow){
  constexpr int E = P/64;
  int lane = threadIdx.x & 63;
  float dl[E];
  float b1=FLT_MAX, b2=FLT_MAX;
  unsigned i1=0xFFFFFFFFu, i2=0xFFFFFFFFu, consumed=0u;
  #pragma unroll
  for(int i=0;i<E;i++){
    unsigned n = i*64 + lane;
    float v = sqdist(qx,qy,qz,p[n*3],p[n*3+1],p[n*3+2]);
    dl[i] = v;
    bool lt1 = v<b1, lt2 = v<b2;
    float    nb2 = lt1 ? b1 : (lt2 ? v : b2);
    unsigned ni2 = lt1 ? i1 : (lt2 ? n : i2);
    b1 = lt1 ? v : b1; i1 = lt1 ? n : i1;
    b2 = nb2; i2 = ni2;
  }
  for(int j=0;j<KK;j++){
    int sel = wave_argmin_f32(b1, i1);
    if(lane==0) outRow[j] = sel;
    if((sel & 63) == lane){
      consumed |= 1u << (sel >> 6);
      b1 = b2; i1 = i2;
      b2 = FLT_MAX; i2 = 0xFFFFFFFFu;
      if(b1 == FLT_MAX){
        #pragma unroll
        for(int i=0;i<E;i++){
          float v = ((consumed>>i)&1u) ? FLT_MAX : dl[i];
          unsigned n = i*64 + lane;
          bool lt1 = v<b1, lt2 = v<b2;
          float    nb2 = lt1 ? b1 : (lt2 ? v : b2);
          unsigned ni2 = lt1 ? i1 : (lt2 ? n : i2);
          b1 = lt1 ? v : b1; i1 = lt1 ? n : i1;
          b2 = nb2; i2 = ni2;
        }
      }
    }
  }
}

// wave-local transcription of pass1_body<64,NPTS,1> (faithful: verified index-by-index)
__device__ void pass1a_wave(int bq, const float* __restrict__ feats,
                            const int* knnrow, int ci, const float* __restrict__ WT,
                            float* __restrict__ hmax, float* __restrict__ hmin,
                            float* __restrict__ part,
                            const float* __restrict__ accS, const float* __restrict__ accQ,
                            const float* __restrict__ bg, const float* __restrict__ bb,
                            char* smem){
  constexpr int C=64, O=128, C4=16, OG=16, LDC=68;
  float* gfp = (float*)smem;            // KK*LDC
  float* cf  = gfp + KK*LDC;            // C
  float* sa  = cf + C;                  // C
  float* sbb = sa + C;                  // C
  float* sct = sbb + C;                 // O
  int lane = threadIdx.x & 63;
  int b = bq >> 8;                      // / NS0
  const float* fb = feats + (size_t)b*NPTS*C;
  {
    float S_=accS[lane], Q_=accQ[lane];
    float m = S_/MROWS, vv = Q_/MROWS - m*m; if(vv<0.f) vv=0.f;
    float a = rsqrtf(vv+EPSV)*bg[lane];
    float sh = bb[lane] - m*a;
    sa[lane]=a; sbb[lane]=sh;
    float raw = fb[(size_t)ci*C + lane];
    float cv = a*raw + sh;
    cf[lane] = cv>0.f ? cv : 0.f;
  }
  wave_sync();
  for(int i=lane; i<KK*C4; i+=64){
    int k = i>>4, d4 = i&15;
    size_t row = (size_t)knnrow[k]*C;
    float4 a4 = *(const float4*)&sa[d4*4];
    float4 s4 = *(const float4*)&sbb[d4*4];
    float4 c4 = *(const float4*)&cf[d4*4];
    float4 g  = ((const float4*)(fb + row))[d4];
    float gx = a4.x*g.x+s4.x; gx = gx>0.f?gx:0.f;
    float gy = a4.y*g.y+s4.y; gy = gy>0.f?gy:0.f;
    float gz = a4.z*g.z+s4.z; gz = gz>0.f?gz:0.f;
    float gw = a4.w*g.w+s4.w; gw = gw>0.f?gw:0.f;
    float4 r; r.x=gx-c4.x; r.y=gy-c4.y; r.z=gz-c4.z; r.w=gw-c4.w;
    *(float4*)&gfp[k*LDC + d4*4] = r;
  }
  wave_sync();
  {
    int o2 = lane*2;
    float ct0=0.f, ct1=0.f;
    for(int c=0;c<C;c+=4){
      float4 c4 = *(const float4*)&cf[c];
      #pragma unroll
      for(int t=0;t<4;t++){
        float cv = ((const float*)&c4)[t];
        float2 wh = *(const float2*)&WT[(size_t)(C+c+t)*O + o2];
        ct0 += cv*wh.x; ct1 += cv*wh.y;
      }
    }
    sct[o2]=ct0; sct[o2+1]=ct1;
  }
  wave_sync();
  int kg = lane >> 4;
  int og = lane & 15;
  float acc[8][8];
  #pragma unroll
  for(int a=0;a<8;a++)
    #pragma unroll
    for(int bb2=0;bb2<8;bb2++) acc[a][bb2]=0.f;
  for(int dc=0; dc<C4; dc++){
    float4 g4[8];
    #pragma unroll
    for(int jk=0;jk<8;jk++) g4[jk] = *(const float4*)&gfp[(kg*8+jk)*LDC + dc*4];
    #pragma unroll
    for(int t=0;t<4;t++){
      const float* wrow = WT + (size_t)(dc*4+t)*O + og*8;
      float4 wa = *(const float4*)wrow;
      float4 wb = *(const float4*)(wrow+4);
      #pragma unroll
      for(int jk=0;jk<8;jk++){
        float gs = ((const float*)&g4[jk])[t];
        acc[jk][0] += gs*wa.x; acc[jk][1] += gs*wa.y; acc[jk][2] += gs*wa.z; acc[jk][3] += gs*wa.w;
        acc[jk][4] += gs*wb.x; acc[jk][5] += gs*wb.y; acc[jk][6] += gs*wb.z; acc[jk][7] += gs*wb.w;
      }
    }
  }
  float tmx[8],tmn[8],tsm[8],tsq[8];
  #pragma unroll
  for(int jo=0;jo<8;jo++){
    int o = og*8+jo;
    float ct = sct[o];
    float s=0.f,q=0.f,mx=-FLT_MAX,mn=FLT_MAX;
    #pragma unroll
    for(int jk=0;jk<8;jk++){
      float h = acc[jk][jo] + ct;
      s+=h; q+=h*h; mx=fmaxf(mx,h); mn=fminf(mn,h);
    }
    tmx[jo]=mx; tmn[jo]=mn; tsm[jo]=s; tsq[jo]=q;
  }
  #pragma unroll
  for(int jo=0;jo<8;jo++){
    tmx[jo]=fmaxf(tmx[jo],__shfl_xor(tmx[jo],16)); tmx[jo]=fmaxf(tmx[jo],__shfl_xor(tmx[jo],32));
    tmn[jo]=fminf(tmn[jo],__shfl_xor(tmn[jo],16)); tmn[jo]=fminf(tmn[jo],__shfl_xor(tmn[jo],32));
    tsm[jo]+=__shfl_xor(tsm[jo],16); tsm[jo]+=__shfl_xor(tsm[jo],32);
    tsq[jo]+=__shfl_xor(tsq[jo],16); tsq[jo]+=__shfl_xor(tsq[jo],32);
  }
  if(lane<OG){
    #pragma unroll
    for(int jo=0;jo<8;jo++){
      int o = lane*8+jo;
      hmax[(size_t)bq*O+o]=tmx[jo]; hmin[(size_t)bq*O+o]=tmn[jo];
      part[(size_t)bq*2*O+o]=tsm[jo]; part[(size_t)bq*2*O+O+o]=tsq[jo];
    }
  }
}

// block-level pass1 (used by L6 / MODE2 path)
template<int C, int P, int MODE>
__device__ void pass1_body(int bq, const float* __restrict__ feats, const float* __restrict__ feats2,
                           const int* knnrow, int ci, const float* __restrict__ WT,
                           float* __restrict__ hmax, float* __restrict__ hmin,
                           float* __restrict__ part, int S,
                           const float* __restrict__ accS, const float* __restrict__ accQ,
                           const float* __restrict__ bg, const float* __restrict__ bb,
                           char* smem){
  constexpr int O   = 2*C;
  constexpr int TPB = C;
  constexpr int C4  = C/4;
  constexpr int OG  = O/8;
  constexpr int LDC = C+4;
  float* gfp = (float*)smem;            // KK*LDC
  float* cf  = gfp + KK*LDC;            // C
  float* sa  = cf + C;                  // C
  float* sbb = sa + C;                  // C
  float* sct = sbb + C;                 // O
  int tid = threadIdx.x;
  int b = bq / S;
  const float* fb = feats + (size_t)b*P*C;
  const float* fb2 = (MODE==2) ? feats2 + (size_t)b*P*C : nullptr;
  {
    float Mv = (MODE==1) ? MROWS : M0F;
    float S_=accS[tid], Q_=accQ[tid];
    float m = S_/Mv, vv = Q_/Mv - m*m; if(vv<0.f) vv=0.f;
    float a = rsqrtf(vv+EPSV)*bg[tid];
    float sh = bb[tid] - m*a;
    sa[tid]=a; sbb[tid]=sh;
    float raw;
    if(MODE==1) raw = fb[(size_t)ci*C + tid];
    else        raw = (a>=0.f) ? fb[(size_t)ci*C + tid] : fb2[(size_t)ci*C + tid];
    float cv = a*raw + sh;
    cf[tid] = cv>0.f ? cv : 0.f;
  }
  __syncthreads();
  for(int i=tid; i<KK*C4; i+=TPB){
    int k = i/C4, d4 = i - k*C4;
    size_t row = (size_t)knnrow[k]*C;
    float4 a4 = *(const float4*)&sa[d4*4];
    float4 s4 = *(const float4*)&sbb[d4*4];
    float4 c4 = *(const float4*)&cf[d4*4];
    float4 g  = ((const float4*)(fb + row))[d4];
    float4 r;
    if(MODE==2){
      float4 g2 = ((const float4*)(fb2 + row))[d4];
      float gx = (a4.x>=0.f? g.x : g2.x)*a4.x + s4.x; gx = gx>0.f?gx:0.f;
      float gy = (a4.y>=0.f? g.y : g2.y)*a4.y + s4.y; gy = gy>0.f?gy:0.f;
      float gz = (a4.z>=0.f? g.z : g2.z)*a4.z + s4.z; gz = gz>0.f?gz:0.f;
      float gw = (a4.w>=0.f? g.w : g2.w)*a4.w + s4.w; gw = gw>0.f?gw:0.f;
      r.x=gx-c4.x; r.y=gy-c4.y; r.z=gz-c4.z; r.w=gw-c4.w;
    } else {
      float gx = a4.x*g.x+s4.x; gx = gx>0.f?gx:0.f;
      float gy = a4.y*g.y+s4.y; gy = gy>0.f?gy:0.f;
      float gz = a4.z*g.z+s4.z; gz = gz>0.f?gz:0.f;
      float gw = a4.w*g.w+s4.w; gw = gw>0.f?gw:0.f;
      r.x=gx-c4.x; r.y=gy-c4.y; r.z=gz-c4.z; r.w=gw-c4.w;
    }
    *(float4*)&gfp[k*LDC + d4*4] = r;
  }
  __syncthreads();
  {
    int o2 = tid*2;
    float ct0=0.f, ct1=0.f;
    for(int c=0;c<C;c+=4){
      float4 c4 = *(const float4*)&cf[c];
      #pragma unroll
      for(int t=0;t<4;t++){
        float cv = ((const float*)&c4)[t];
        float2 wh = *(const float2*)&WT[(size_t)(C+c+t)*O + o2];
        ct0 += cv*wh.x; ct1 += cv*wh.y;
      }
    }
    sct[o2]=ct0; sct[o2+1]=ct1;
  }
  __syncthreads();
  int kg = tid / OG;
  int og = tid % OG;
  float acc[8][8];
  #pragma unroll
  for(int a=0;a<8;a++)
    #pragma unroll
    for(int bb2=0;bb2<8;bb2++) acc[a][bb2]=0.f;
  for(int dc=0; dc<C4; dc++){
    float4 g4[8];
    #pragma unroll
    for(int jk=0;jk<8;jk++) g4[jk] = *(const float4*)&gfp[(kg*8+jk)*LDC + dc*4];
    #pragma unroll
    for(int t=0;t<4;t++){
      const float* wrow = WT + (size_t)(dc*4+t)*O + og*8;
      float4 wa = *(const float4*)wrow;
      float4 wb = *(const float4*)(wrow+4);
      #pragma unroll
      for(int jk=0;jk<8;jk++){
        float gs = ((const float*)&g4[jk])[t];
        acc[jk][0] += gs*wa.x; acc[jk][1] += gs*wa.y; acc[jk][2] += gs*wa.z; acc[jk][3] += gs*wa.w;
        acc[jk][4] += gs*wb.x; acc[jk][5] += gs*wb.y; acc[jk][6] += gs*wb.z; acc[jk][7] += gs*wb.w;
      }
    }
  }
  float tmx[8],tmn[8],tsm[8],tsq[8];
  #pragma unroll
  for(int jo=0;jo<8;jo++){
    int o = og*8+jo;
    float ct = sct[o];
    float s=0.f,q=0.f,mx=-FLT_MAX,mn=FLT_MAX;
    #pragma unroll
    for(int jk=0;jk<8;jk++){
      float h = acc[jk][jo] + ct;
      s+=h; q+=h*h; mx=fmaxf(mx,h); mn=fminf(mn,h);
    }
    tmx[jo]=mx; tmn[jo]=mn; tsm[jo]=s; tsq[jo]=q;
  }
  #pragma unroll
  for(int jo=0;jo<8;jo++){
    tmx[jo]=fmaxf(tmx[jo],__shfl_xor(tmx[jo],32));
    tmn[jo]=fminf(tmn[jo],__shfl_xor(tmn[jo],32));
    tsm[jo]+=__shfl_xor(tsm[jo],32);
    tsq[jo]+=__shfl_xor(tsq[jo],32);
  }
  int wv = tid>>6;
  if((tid&63)<32){
    int og_ = tid&31;
    size_t rb = (size_t)bq*2 + wv;        // doubled row per wave; combined downstream
    #pragma unroll
    for(int jo=0;jo<8;jo++){
      int o = og_*8+jo;
      hmax[rb*O+o]=tmx[jo]; hmin[rb*O+o]=tmn[jo];
      part[rb*2*O+o]=tsm[jo]; part[rb*2*O+O+o]=tsq[jo];
    }
  }
}

// ================= kernels =================

// L1: embed1+BN1-stats (0..511) || wt (512..831). Accumulators pre-zeroed by hipMemsetAsync.
__global__ __launch_bounds__(256) void k_embed1_wt(const float* __restrict__ x, const float* __restrict__ w1,
                         float* __restrict__ coords, float* __restrict__ t1,
                         const float* __restrict__ wsg0, float* __restrict__ wt0,
                         const float* __restrict__ wsg1, float* __restrict__ wt1,
                         float* __restrict__ acc1S, float* __restrict__ acc1Q){
  if(blockIdx.x < 512) embed1_body(blockIdx.x, x, w1, coords, t1, acc1S, acc1Q);
  else wt_body((blockIdx.x-512)*256 + threadIdx.x, wsg0, wt0, wsg1, wt1);
}

// L2: embed2 + fused BN2 stats (own kernel -> t2/acc2 are prior-kernel data for mega)
__global__ __launch_bounds__(256, 1) void k_embed2(const float* __restrict__ t1, const float* __restrict__ w2,
                         const float* __restrict__ acc1S, const float* __restrict__ acc1Q,
                         const float* __restrict__ g1, const float* __restrict__ b1,
                         float* __restrict__ t2,
                         float* __restrict__ acc2S, float* __restrict__ acc2Q){
  extern __shared__ char smem[];
  __shared__ float ls[64], lq[64];
  embed2_body(blockIdx.x, t1, w2, acc1S, acc1Q, g1, b1, t2, acc2S, acc2Q, ls, lq, smem);
}

// MEGA (replaces fps0-kernel + L4): deadlock-free ticket queue.
//   tickets [0,16):   fps0 per batch (v4 frozen loop + release publish every 32 iters)
//   tickets [16,20):  fps1 quads (wave-local; waits prog[b]==256; atomic xyz0 staging)
//   tickets [20,1044): pass1a quads — 4 (b,s)-jobs/block, one per wave; waits prog[b]>=s+1
// Deadlock-free: tickets claimed in order => any waiter's producers hold earlier tickets
// on resident blocks; fps0 never waits. All flag-guarded data read via agent atomics.
#define NT_FPS0  16
#define NT_FPS1E 20
#define NT_ALL   1044
__global__ __launch_bounds__(256) void k_mega(const float* __restrict__ x,
                         int* __restrict__ fps0i, float* __restrict__ xyz0,
                         const float* __restrict__ t2,
                         const float* __restrict__ acc2S, const float* __restrict__ acc2Q,
                         const float* __restrict__ coords, const float* __restrict__ wt0,
                         float* __restrict__ hmax0, float* __restrict__ hmin0, float* __restrict__ part0,
                         const float* __restrict__ g2, const float* __restrict__ b2,
                         int* __restrict__ fps1i, float* __restrict__ xyz1,
                         int* prog, int* tck){
  extern __shared__ __align__(16) char SU[];
  __shared__ int sTk;
  int tid = threadIdx.x;
  for(;;){
    if(tid==0) sTk = atomicAdd(tck, 1);
    __syncthreads();
    int tk = sTk;
    __syncthreads();
    if(tk >= NT_ALL) return;
    if(tk < NT_FPS0){
      fps_body<NPTS,NS0,256>(tk, x, fps0i, xyz0, SU, prog);
    } else if(tk < NT_FPS1E){
      int wv = tid>>6;
      int b4 = (tk-NT_FPS0)*4 + wv;
      wait_ge(prog + b4, NS0);
      fps1_wave<NS0,NS1>(b4, xyz0, fps1i, xyz1, SU + wv*4608);
    } else {
      int q = tk - NT_FPS1E;
      int wv = tid>>6;
      int b = q & 15;
      int s = ((q>>4)<<2) + wv;
      int bq = (b<<8) + s;
      char* W = SU + wv*10112;
      int* sknn = (int*)(W + 9984);
      wait_ge(prog + b, s + 1);
      float qx = __hip_atomic_load(xyz0+(size_t)bq*3+0, __ATOMIC_RELAXED, __HIP_MEMORY_SCOPE_AGENT);
      float qy = __hip_atomic_load(xyz0+(size_t)bq*3+1, __ATOMIC_RELAXED, __HIP_MEMORY_SCOPE_AGENT);
      float qz = __hip_atomic_load(xyz0+(size_t)bq*3+2, __ATOMIC_RELAXED, __HIP_MEMORY_SCOPE_AGENT);
      int   ci = __hip_atomic_load(fps0i+bq, __ATOMIC_RELAXED, __HIP_MEMORY_SCOPE_AGENT);
      knn_compute<NPTS>(coords + (size_t)b*NPTS*3, qx, qy, qz, sknn);
      wave_sync();
      pass1a_wave(bq, t2, sknn, ci, wt0, hmax0, hmin0, part0, acc2S, acc2Q, g2, b2, W);
    }
  }
}

// L5: row-coalesced partial-sum reduce: block = 64 rows; one atomic per column
__global__ __launch_bounds__(256) void k_statsB(const float* __restrict__ part, int W,
                                                float* __restrict__ acc){
  int tid = threadIdx.x;
  int r0 = blockIdx.x*64;
  for(int c=tid; c<W; c+=256){
    float a=0.f;
    for(int r=0;r<64;r++) a += part[(size_t)(r0+r)*W + c];
    atomicAdd(acc+c, a);
  }
}

// L6: FUSED knn1+pass1b (2048 blocks x 128 thr)
__global__ __launch_bounds__(128, 2) void k_knn1_p1b(const float* __restrict__ xyz0,
                         const float* __restrict__ xyz1, const int* __restrict__ fps1,
                         const float* __restrict__ hmax0, const float* __restrict__ hmin0,
                         const float* __restrict__ wt1,
                         float* __restrict__ hmax1, float* __restrict__ hmin1, float* __restrict__ part1,
                         const float* __restrict__ accB0S, const float* __restrict__ accB0Q,
                         const float* __restrict__ gsg0, const float* __restrict__ bsg0){
  __shared__ __align__(16) char SU[19584];   // pass1b: 19456 + sknn 128
  int bq = blockIdx.x;
  int b = bq / NS1;
  int* sknn = (int*)(SU + 19456);
  if(threadIdx.x < 64){
    const float* pts = xyz0 + (size_t)b*NS0*3;
    float qx=xyz1[(size_t)bq*3], qy=xyz1[(size_t)bq*3+1], qz=xyz1[(size_t)bq*3+2];
    knn_compute<NS0>(pts, qx, qy, qz, sknn);
  }
  __syncthreads();
  pass1_body<128,NS0,2>(bq, hmax0, hmin0, sknn, fps1[bq], wt1, hmax1, hmin1, part1, NS1,
                        accB0S, accB0Q, gsg0, bsg0, SU);
}

// L8: stage-1 postmax + transpose via LDS tile; combines the doubled stat rows.
__global__ __launch_bounds__(256) void k_post1tr(const float* __restrict__ hmax, const float* __restrict__ hmin,
        const float* __restrict__ aS, const float* __restrict__ aQ,
        const float* __restrict__ g, const float* __restrict__ bb, float* __restrict__ out){
  __shared__ float ssc[64], ssh[64];
  __shared__ float tile[64][129];
  int tid = threadIdx.x;
  int blk = blockIdx.x; int b = blk>>2; int c0 = (blk&3)*64;
  if(tid<64){
    int o = c0+tid;
    float m = aS[o]/M1F, v = aQ[o]/M1F - m*m; if(v<0.f) v=0.f;
    float sc = rsqrtf(v+EPSV)*g[o];
    ssc[tid]=sc; ssh[tid]=bb[o]-m*sc;
  }
  __syncthreads();
  for(int i=tid; i<128*64; i+=256){
    int r=i>>6, ch=i&63;
    size_t rb = (size_t)(b*NS1+r)*2;
    float sc = ssc[ch];
    float va = hmax[rb*256 + c0+ch], vb = hmax[(rb+1)*256 + c0+ch];
    float wa = hmin[rb*256 + c0+ch], wb = hmin[(rb+1)*256 + c0+ch];
    float h = (sc>=0.f) ? fmaxf(va,vb) : fminf(wa,wb);
    float v = h*sc + ssh[ch];
    tile[ch][r] = v>0.f ? v : 0.f;
  }
  __syncthreads();
  for(int i=tid; i<64*128; i+=256){
    int ch=i>>7, s=i&127;
    out[(size_t)b*(256*NS1) + (size_t)(c0+ch)*NS1 + s] = tile[ch][s];
  }
}

extern "C" void kernel_launch(void* const* d_in, const int* in_sizes, int n_in,
                              void* d_out, int out_size, void* d_ws, size_t ws_size,
                              hipStream_t stream){
  const float* x    = (const float*)d_in[0];
  const float* w1   = (const float*)d_in[1];
  const float* g1   = (const float*)d_in[2];
  const float* b1   = (const float*)d_in[3];
  const float* w2   = (const float*)d_in[4];
  const float* g2   = (const float*)d_in[5];
  const float* b2   = (const float*)d_in[6];
  const float* wsg0 = (const float*)d_in[7];
  const float* gsg0 = (const float*)d_in[8];
  const float* bsg0 = (const float*)d_in[9];
  const float* wsg1 = (const float*)d_in[10];
  const float* gsg1 = (const float*)d_in[11];
  const float* bsg1 = (const float*)d_in[12];
  float* out = (float*)d_out;

  float* wsf = (float*)d_ws;
  float* coords = wsf;                    wsf += BATCH*NPTS*3;
  float* t1     = wsf;                    wsf += BATCH*NPTS*64;   // ALIASED: part1 after L2
  float* t2     = wsf;                    wsf += BATCH*NPTS*64;   // ALIASED: hmax1|hmin1 after mega
  float* acc1S=wsf; wsf+=64;  float* acc1Q=wsf; wsf+=64;          // contiguous accum+ctrl block
  float* acc2S=wsf; wsf+=64;  float* acc2Q=wsf; wsf+=64;
  float* accB0=wsf; wsf+=256;                                      // [S x128][Q x128]
  float* accB1=wsf; wsf+=512;                                      // [S x256][Q x256]
  int*   prog = (int*)wsf;                wsf += 16;               // fps0 progress per batch
  int*   tck  = (int*)wsf;                wsf += 1;                // ticket counter
  wsf += 15;                                                       // pad ctrl to 32 ints
  int*   fps0 = (int*)wsf;                wsf += BATCH*NS0;
  float* xyz0 = wsf;                      wsf += BATCH*NS0*3;
  float* hmax0= wsf;                      wsf += BATCH*NS0*128;
  float* hmin0= wsf;                      wsf += BATCH*NS0*128;
  float* part0= wsf;                      wsf += BATCH*NS0*2*128;
  int*   fps1 = (int*)wsf;                wsf += BATCH*NS1;
  float* xyz1 = wsf;                      wsf += BATCH*NS1*3;
  float* wt0  = wsf;                      wsf += 128*128;
  float* wt1  = wsf;                      wsf += 256*256;
  // aliases (t1 dead after L2; t2 dead after mega)
  float* part1 = t1;                      // (NB1*2) x 512 floats == |t1|
  float* hmax1 = t2;                      // (NB1*2) x 256
  float* hmin1 = t2 + BATCH*NS1*2*256;

  const int DYN_E2   = (4096 + 256)*4;    // embed2: fin 4096 + 4x64 params
  const int DYN_MEGA = 4*10112;           // >= fps0 25664, 4x p1a 40448, 4x fps1 18432

  // L0: zero accumulators + control block (1024 floats + 32 ints), graph-capture safe
  hipMemsetAsync(acc1S, 0, (1024+32)*sizeof(float), stream);
  // L1: embed1 + fused BN1 stats || weight transposes
  k_embed1_wt<<<dim3(832), dim3(256), 0, stream>>>(x, w1, coords, t1, wsg0, wt0, wsg1, wt1,
                                                   acc1S, acc1Q);
  // L2: embed2 + fused BN2 stats (exposed ~10us; makes t2/acc2 prior-kernel data)
  k_embed2<<<dim3(512), dim3(256), DYN_E2, stream>>>(t1, w2, acc1S, acc1Q, g1, b1,
                                                     t2, acc2S, acc2Q);
  // MEGA: fps0 || fps1 || streamed knn0+pass1a (consumers trail fps0 by <=32 centers)
  k_mega<<<dim3(NT_ALL), dim3(256), DYN_MEGA, stream>>>(x, fps0, xyz0,
                                                  t2, acc2S, acc2Q,
                                                  coords, wt0, hmax0, hmin0, part0, g2, b2,
                                                  fps1, xyz1, prog, tck);
  // L5: reduce part0 -> accB0
  k_statsB<<<dim3(64), dim3(256), 0, stream>>>(part0, 256, accB0);
  // L6: fused knn1+pass1b (BN0-select fused; f1 never materialized)
  k_knn1_p1b<<<dim3(BATCH*NS1), dim3(128), 0, stream>>>(xyz0, xyz1, fps1,
                                                  hmax0, hmin0, wt1,
                                                  hmax1, hmin1, part1,
                                                  accB0, accB0+128, gsg0, bsg0);
  // L7: reduce part1 -> accB1
  k_statsB<<<dim3(64), dim3(256), 0, stream>>>(part1, 512, accB1);
  // L8: postmax + transpose -> out
  k_post1tr<<<dim3(64), dim3(256), 0, stream>>>(hmax1, hmin1, accB1, accB1+256, gsg1, bsg1, out);
}

// Round 5
// 436.107 us; speedup vs baseline: 1.0135x; 1.0135x over previous
//
#include <hip/hip_runtime.h>
#include <float.h>

#define BATCH 16
#define NPTS  2048
#define NS0   256
#define NS1   128
#define KK    32
#define EPSV  1e-5f
#define MROWS 32768.0f   // BATCH*NPTS
#define M0F   131072.0f  // BATCH*NS0*KK
#define M1F   65536.0f   // BATCH*NS1*KK

// exact numpy-order squared distance: ((dx*dx + dy*dy) + dz*dz), no FMA contraction
__device__ __forceinline__ float sqdist(float ax,float ay,float az,float bx,float by,float bz){
  float dx=__fsub_rn(ax,bx), dy=__fsub_rn(ay,by), dz=__fsub_rn(az,bz);
  return __fadd_rn(__fadd_rn(__fmul_rn(dx,dx),__fmul_rn(dy,dy)),__fmul_rn(dz,dz));
}

// ---- native f32/u32 DPP ladders (cheap wave64 reduce; winner broadcast via readlane 63)
template<int CTRL,int RM>
__device__ __forceinline__ float dpp_fmax_s(float x){
  int t = __builtin_amdgcn_update_dpp((int)0xFF800000, __float_as_int(x), CTRL, RM, 0xf, false);
  return fmaxf(x, __int_as_float(t));
}
template<int CTRL,int RM>
__device__ __forceinline__ unsigned dpp_umin_s(unsigned x){
  unsigned t = (unsigned)__builtin_amdgcn_update_dpp(-1, (int)x, CTRL, RM, 0xf, false);
  return t<x ? t : x;
}
// argmax over (v,idx): max value, tie -> lowest idx (matches np.argmax first-occurrence)
// FROZEN with fps_body v4 — do not replace with packed u64 ladder (r1: +34us regression).
__device__ __forceinline__ void wave_argmax_f32(float v, unsigned idx, float& mall, int& sel){
  float m=v;
  m=dpp_fmax_s<0x111,0xf>(m); m=dpp_fmax_s<0x112,0xf>(m); m=dpp_fmax_s<0x114,0xf>(m);
  m=dpp_fmax_s<0x118,0xf>(m); m=dpp_fmax_s<0x142,0xa>(m); m=dpp_fmax_s<0x143,0xc>(m);
  mall = __int_as_float(__builtin_amdgcn_readlane(__float_as_int(m),63));
  unsigned c = (v==mall)? idx : 0xFFFFFFFFu;
  c=dpp_umin_s<0x111,0xf>(c); c=dpp_umin_s<0x112,0xf>(c); c=dpp_umin_s<0x114,0xf>(c);
  c=dpp_umin_s<0x118,0xf>(c); c=dpp_umin_s<0x142,0xa>(c); c=dpp_umin_s<0x143,0xc>(c);
  sel = (int)(unsigned)__builtin_amdgcn_readlane((int)c,63);
}

// ---- packed u64 argmin (kept: neutral-to-positive in KNN tournaments, r1/r2) ----
template<int CTRL,int RM>
__device__ __forceinline__ unsigned long long dpp_umin64_s(unsigned long long x){
  unsigned tlo=(unsigned)__builtin_amdgcn_update_dpp(-1,(int)(unsigned)x,        CTRL,RM,0xf,false);
  unsigned thi=(unsigned)__builtin_amdgcn_update_dpp(-1,(int)(unsigned)(x>>32), CTRL,RM,0xf,false);
  unsigned long long t=((unsigned long long)thi<<32)|tlo;
  return t<x ? t : x;
}
__device__ __forceinline__ int wave_argmin_f32(float v, unsigned idx){
  unsigned long long k = ((unsigned long long)__float_as_uint(v)<<32) | (unsigned long long)idx;
  k=dpp_umin64_s<0x111,0xf>(k); k=dpp_umin64_s<0x112,0xf>(k); k=dpp_umin64_s<0x114,0xf>(k);
  k=dpp_umin64_s<0x118,0xf>(k); k=dpp_umin64_s<0x142,0xa>(k); k=dpp_umin64_s<0x143,0xc>(k);
  return (int)(unsigned)__builtin_amdgcn_readlane((int)(unsigned)k,63);
}

// ---- wave-local sync: orders LDS writes->reads within a converged wave ----
__device__ __forceinline__ void wave_sync(){
  asm volatile("s_waitcnt lgkmcnt(0)" ::: "memory");
  __builtin_amdgcn_sched_barrier(0);
}

// ---- relaxed agent-scope poll, BOUNDED. r5 fix vs r4: LANE-0-ONLY atomic load
// (r4: all 64 lanes issued the atomic -> 64x traffic to one cacheline from ~2000
// spinning waves = fabric congestion that slowed fps0's publishes) + longer sleep.
__device__ __forceinline__ void wait_ge(int* flag, int want){
  int lane = threadIdx.x & 63;
  for(int t=0; t<(1<<20); ++t){
    int v = 0;
    if(lane==0) v = __hip_atomic_load(flag, __ATOMIC_RELAXED, __HIP_MEMORY_SCOPE_AGENT);
    v = __builtin_amdgcn_readfirstlane(v);
    if(v >= want) break;
    __builtin_amdgcn_s_sleep(32);
  }
  asm volatile("" ::: "memory");
}

// ================= device bodies =================

// embed1 v3: 64 points/block, LDS-staged coalesced t1 writes + FUSED BN1 stats
__device__ void embed1_body(int bid, const float* __restrict__ x, const float* __restrict__ w1,
                            float* __restrict__ coords, float* __restrict__ t1,
                            float* __restrict__ accS, float* __restrict__ accQ){
  __shared__ float w[192];
  __shared__ float xs[3][64];
  __shared__ float fin[64][65];
  __shared__ float ls[64], lq[64];
  int tid = threadIdx.x;
  if (tid < 192) w[tid] = w1[tid];
  int base = bid*64;
  int b = base / NPTS, n0 = base % NPTS;
  if (tid < 192){
    int ch = tid>>6, i = tid&63;
    xs[ch][i] = x[((size_t)b*3+ch)*NPTS + n0 + i];
  } else {
    int t = tid - 192;
    ls[t]=0.f; lq[t]=0.f;
  }
  __syncthreads();
  if (tid < 64){
    coords[(size_t)(base+tid)*3+0]=xs[0][tid];
    coords[(size_t)(base+tid)*3+1]=xs[1][tid];
    coords[(size_t)(base+tid)*3+2]=xs[2][tid];
  }
  int p = tid>>2, c0 = (tid&3)<<4;
  float cx=xs[0][p], cy=xs[1][p], cz=xs[2][p];
  #pragma unroll
  for(int j=0;j<16;j++){
    int c = c0+j;
    fin[p][c] = cx*w[c*3+0] + cy*w[c*3+1] + cz*w[c*3+2];
  }
  __syncthreads();
  float s_=0.f, q_=0.f;
  for(int i=tid;i<4096;i+=256){
    int pp=i>>6, c=i&63;
    float v = fin[pp][c];
    t1[(size_t)base*64 + i] = v;
    s_+=v; q_+=v*v;
  }
  atomicAdd(&ls[tid&63], s_);
  atomicAdd(&lq[tid&63], q_);
  __syncthreads();
  if(tid<64){ atomicAdd(accS+tid, ls[tid]); atomicAdd(accQ+tid, lq[tid]); }
}

__device__ void wt_body(int gid, const float* __restrict__ w0, float* __restrict__ wt0,
                        const float* __restrict__ w1, float* __restrict__ wt1){
  if(gid < 128*128){
    int o = gid % 128, c = gid / 128;
    wt0[gid] = w0[o*128 + c];
  } else {
    int g2 = gid - 128*128;
    if(g2 >= 256*256) return;
    int o = g2 % 256, c = g2 / 256;
    wt1[g2] = w1[o*256 + c];
  }
}

// embed2 + fused BN2 stats (own kernel: outputs are prior-kernel data for the mega)
__device__ void embed2_body(int bid, const float* __restrict__ t1, const float* __restrict__ w2,
                            const float* __restrict__ accS, const float* __restrict__ accQ,
                            const float* __restrict__ g1, const float* __restrict__ b1,
                            float* __restrict__ t2,
                            float* __restrict__ acc2S, float* __restrict__ acc2Q,
                            float* ls, float* lq, char* smem){
  float (*fin)[64] = (float(*)[64])smem;
  float* sm = (float*)smem + 4096;
  float* sr = sm+64; float* sg = sr+64; float* sb = sg+64;
  int tid = threadIdx.x;
  if (tid<64){
    float S=accS[tid], Q=accQ[tid];
    float m = S/MROWS, v = Q/MROWS - m*m; if(v<0.f) v=0.f;
    sm[tid]=m; sr[tid]=rsqrtf(v+EPSV); sg[tid]=g1[tid]; sb[tid]=b1[tid];
    ls[tid]=0.f; lq[tid]=0.f;
  }
  __syncthreads();
  int base = bid*64;
  for(int i=tid;i<4096;i+=256){
    int p=i>>6, c=i&63;
    float v = t1[(size_t)(base+p)*64 + c];
    v = (v - sm[c])*sr[c]*sg[c] + sb[c];
    fin[p][c] = v>0.f ? v : 0.f;
  }
  __syncthreads();
  int o = tid & 63, p0 = tid>>6;
  float acc[16];
  #pragma unroll
  for(int i=0;i<16;i++) acc[i]=0.f;
  for(int cc=0; cc<64; cc+=4){
    float4 wv = *(const float4*)(w2 + o*64 + cc);
    #pragma unroll
    for(int i=0;i<16;i++){
      float4 f4 = *(const float4*)&fin[p0 + i*4][cc];
      acc[i] += f4.x*wv.x + f4.y*wv.y + f4.z*wv.z + f4.w*wv.w;
    }
  }
  float s=0.f,q=0.f;
  #pragma unroll
  for(int i=0;i<16;i++){
    float v = acc[i];
    t2[(size_t)(base+p0+i*4)*64 + o] = v;
    s+=v; q+=v*v;
  }
  atomicAdd(&ls[o], s);
  atomicAdd(&lq[o], q);
  __syncthreads();
  if(tid<64){ atomicAdd(acc2S+tid, ls[tid]); atomicAdd(acc2Q+tid, lq[tid]); }
}

// multi-wave FPS v4 (FROZEN loop: measured 124-127us) + tid0-only incremental publish.
// Runs at s_setprio(3) inside the mega so its latency-critical dependent chain wins
// SIMD arbitration over co-resident GEMM consumer waves (r4: sharing cost ~1.7x).
template<int P, int S, int T>
__device__ void fps_body(int b, const float* __restrict__ x, int* __restrict__ outIdx,
                         float* __restrict__ outXyz, char* smem, int* prog){
  constexpr int PPT = P/T;
  constexpr int NW  = T/64;
  float* sx=(float*)smem; float* sy=sx+P; float* sz=sy+P;
  int* sidx=(int*)(sz+P);
  unsigned long long* rv64=(unsigned long long*)(sidx+S);
  int tid = threadIdx.x;
  const float* xb = x + (size_t)b*3*P;
  float px[PPT], py[PPT], pz[PPT], dist[PPT];
  #pragma unroll
  for(int i=0;i<PPT;i++){
    int n = i*T + tid;
    float X=xb[n], Y=xb[P+n], Z=xb[2*P+n];
    px[i]=X; py[i]=Y; pz[i]=Z; dist[i]=1e10f;
    sx[n]=X; sy[n]=Y; sz[n]=Z;
  }
  __syncthreads();
  int cur = 0;
  float cx=sx[0], cy=sy[0], cz=sz[0];
  for(int s=0;s<S;s++){
    if(tid==0){
      sidx[s]=cur;
      size_t o = (size_t)b*S + s;
      outIdx[o]=cur;
      outXyz[o*3+0]=cx; outXyz[o*3+1]=cy; outXyz[o*3+2]=cz;
      if((s&31)==31)
        __hip_atomic_store(prog+b, s+1, __ATOMIC_RELEASE, __HIP_MEMORY_SCOPE_AGENT);
    }
    if(s==S-1) break;
    float bv=-FLT_MAX; int bi=0;
    #pragma unroll
    for(int i=0;i<PPT;i++){
      float d = sqdist(px[i],py[i],pz[i],cx,cy,cz);
      float nd = fminf(dist[i], d);
      dist[i]=nd;
      int n = i*T + tid;
      if(nd>bv){ bv=nd; bi=n; }
    }
    float mall; int sel;
    wave_argmax_f32(bv,(unsigned)bi,mall,sel);
    int sl = s & 1;
    if((tid&63)==0) rv64[sl*NW+(tid>>6)] = ((unsigned long long)__float_as_uint(mall)<<32)|(unsigned)(~sel);
    __syncthreads();
    unsigned long long wk = rv64[sl*NW];
    #pragma unroll
    for(int w=1;w<NW;w++){ unsigned long long t = rv64[sl*NW+w]; if(t>wk) wk=t; }
    cur = (int)(~(unsigned)wk);
    cx=sx[cur]; cy=sy[cur]; cz=sz[cur];
  }
  __syncthreads();
  for(int i=tid; i<S; i+=T){
    int id = sidx[i];
    outIdx[b*S+i] = id;
    outXyz[((size_t)b*S+i)*3+0] = sx[id];
    outXyz[((size_t)b*S+i)*3+1] = sy[id];
    outXyz[((size_t)b*S+i)*3+2] = sz[id];
  }
  __syncthreads();   // all waves' stores drained to L2 at barrier (compiler vmcnt(0))
  if(tid==0)
    __hip_atomic_store(prog+b, S, __ATOMIC_RELEASE, __HIP_MEMORY_SCOPE_AGENT);
}

// single-wave FPS, wave-local; xyz0 staged via agent-scope ATOMIC loads (within-kernel
// cross-XCD data). Also runs at setprio(3) — serial 128-iter chain in the mega tail.
template<int P, int S>
__device__ void fps1_wave(int b, float* __restrict__ pts, int* __restrict__ outIdx,
                          float* __restrict__ outXyz, char* smem){
  constexpr int PPT = P/64;
  float4* sp = (float4*)smem;
  int* sidx = (int*)(smem + P*sizeof(float4));
  int lane = threadIdx.x & 63;
  float* p = pts + (size_t)b*P*3;
  float px[PPT], py[PPT], pz[PPT], dist[PPT];
  #pragma unroll
  for(int i=0;i<PPT;i++){
    int n = i*64 + lane;
    float X=__hip_atomic_load(p+n*3+0, __ATOMIC_RELAXED, __HIP_MEMORY_SCOPE_AGENT);
    float Y=__hip_atomic_load(p+n*3+1, __ATOMIC_RELAXED, __HIP_MEMORY_SCOPE_AGENT);
    float Z=__hip_atomic_load(p+n*3+2, __ATOMIC_RELAXED, __HIP_MEMORY_SCOPE_AGENT);
    px[i]=X; py[i]=Y; pz[i]=Z; dist[i]=1e10f;
    sp[n] = make_float4(X,Y,Z,0.f);
  }
  wave_sync();
  int cur = 0;
  float cx=sp[0].x, cy=sp[0].y, cz=sp[0].z;
  for(int s=0;s<S;s++){
    if(lane==0) sidx[s]=cur;
    if(s==S-1) break;
    float bv=-FLT_MAX; int bi=0;
    #pragma unroll
    for(int i=0;i<PPT;i++){
      float d = sqdist(px[i],py[i],pz[i],cx,cy,cz);
      float nd = fminf(dist[i], d);
      dist[i]=nd;
      int n = i*64 + lane;
      if(nd>bv){ bv=nd; bi=n; }
    }
    float mall; int sel;
    wave_argmax_f32(bv,(unsigned)bi,mall,sel);
    cur = sel;
    float4 cp = sp[cur];
    cx=cp.x; cy=cp.y; cz=cp.z;
  }
  wave_sync();
  for(int i=lane; i<S; i+=64){
    int id = sidx[i];
    float4 cp = sp[id];
    outIdx[b*S+i] = id;
    outXyz[((size_t)b*S+i)*3+0] = cp.x;
    outXyz[((size_t)b*S+i)*3+1] = cp.y;
    outXyz[((size_t)b*S+i)*3+2] = cp.z;
  }
}

// KNN tournament v3: per-lane top-2 cache + consumed bitmask, one wave
template<int P>
__device__ void knn_compute(const float* __restrict__ p, float qx, float qy, float qz,
                            int* outRow){
  constexpr int E = P/64;
  int lane = threadIdx.x & 63;
  float dl[E];
  float b1=FLT_MAX, b2=FLT_MAX;
  unsigned i1=0xFFFFFFFFu, i2=0xFFFFFFFFu, consumed=0u;
  #pragma unroll
  for(int i=0;i<E;i++){
    unsigned n = i*64 + lane;
    float v = sqdist(qx,qy,qz,p[n*3],p[n*3+1],p[n*3+2]);
    dl[i] = v;
    bool lt1 = v<b1, lt2 = v<b2;
    float    nb2 = lt1 ? b1 : (lt2 ? v : b2);
    unsigned ni2 = lt1 ? i1 : (lt2 ? n : i2);
    b1 = lt1 ? v : b1; i1 = lt1 ? n : i1;
    b2 = nb2; i2 = ni2;
  }
  for(int j=0;j<KK;j++){
    int sel = wave_argmin_f32(b1, i1);
    if(lane==0) outRow[j] = sel;
    if((sel & 63) == lane){
      consumed |= 1u << (sel >> 6);
      b1 = b2; i1 = i2;
      b2 = FLT_MAX; i2 = 0xFFFFFFFFu;
      if(b1 == FLT_MAX){
        #pragma unroll
        for(int i=0;i<E;i++){
          float v = ((consumed>>i)&1u) ? FLT_MAX : dl[i];
          unsigned n = i*64 + lane;
          bool lt1 = v<b1, lt2 = v<b2;
          float    nb2 = lt1 ? b1 : (lt2 ? v : b2);
          unsigned ni2 = lt1 ? i1 : (lt2 ? n : i2);
          b1 = lt1 ? v : b1; i1 = lt1 ? n : i1;
          b2 = nb2; i2 = ni2;
        }
      }
    }
  }
}

// wave-local transcription of pass1_body<64,NPTS,1> (faithful: verified index-by-index)
__device__ void pass1a_wave(int bq, const float* __restrict__ feats,
                            const int* knnrow, int ci, const float* __restrict__ WT,
                            float* __restrict__ hmax, float* __restrict__ hmin,
                            float* __restrict__ part,
                            const float* __restrict__ accS, const float* __restrict__ accQ,
                            const float* __restrict__ bg, const float* __restrict__ bb,
                            char* smem){
  constexpr int C=64, O=128, C4=16, OG=16, LDC=68;
  float* gfp = (float*)smem;            // KK*LDC
  float* cf  = gfp + KK*LDC;            // C
  float* sa  = cf + C;                  // C
  float* sbb = sa + C;                  // C
  float* sct = sbb + C;                 // O
  int lane = threadIdx.x & 63;
  int b = bq >> 8;                      // / NS0
  const float* fb = feats + (size_t)b*NPTS*C;
  {
    float S_=accS[lane], Q_=accQ[lane];
    float m = S_/MROWS, vv = Q_/MROWS - m*m; if(vv<0.f) vv=0.f;
    float a = rsqrtf(vv+EPSV)*bg[lane];
    float sh = bb[lane] - m*a;
    sa[lane]=a; sbb[lane]=sh;
    float raw = fb[(size_t)ci*C + lane];
    float cv = a*raw + sh;
    cf[lane] = cv>0.f ? cv : 0.f;
  }
  wave_sync();
  for(int i=lane; i<KK*C4; i+=64){
    int k = i>>4, d4 = i&15;
    size_t row = (size_t)knnrow[k]*C;
    float4 a4 = *(const float4*)&sa[d4*4];
    float4 s4 = *(const float4*)&sbb[d4*4];
    float4 c4 = *(const float4*)&cf[d4*4];
    float4 g  = ((const float4*)(fb + row))[d4];
    float gx = a4.x*g.x+s4.x; gx = gx>0.f?gx:0.f;
    float gy = a4.y*g.y+s4.y; gy = gy>0.f?gy:0.f;
    float gz = a4.z*g.z+s4.z; gz = gz>0.f?gz:0.f;
    float gw = a4.w*g.w+s4.w; gw = gw>0.f?gw:0.f;
    float4 r; r.x=gx-c4.x; r.y=gy-c4.y; r.z=gz-c4.z; r.w=gw-c4.w;
    *(float4*)&gfp[k*LDC + d4*4] = r;
  }
  wave_sync();
  {
    int o2 = lane*2;
    float ct0=0.f, ct1=0.f;
    for(int c=0;c<C;c+=4){
      float4 c4 = *(const float4*)&cf[c];
      #pragma unroll
      for(int t=0;t<4;t++){
        float cv = ((const float*)&c4)[t];
        float2 wh = *(const float2*)&WT[(size_t)(C+c+t)*O + o2];
        ct0 += cv*wh.x; ct1 += cv*wh.y;
      }
    }
    sct[o2]=ct0; sct[o2+1]=ct1;
  }
  wave_sync();
  int kg = lane >> 4;
  int og = lane & 15;
  float acc[8][8];
  #pragma unroll
  for(int a=0;a<8;a++)
    #pragma unroll
    for(int bb2=0;bb2<8;bb2++) acc[a][bb2]=0.f;
  for(int dc=0; dc<C4; dc++){
    float4 g4[8];
    #pragma unroll
    for(int jk=0;jk<8;jk++) g4[jk] = *(const float4*)&gfp[(kg*8+jk)*LDC + dc*4];
    #pragma unroll
    for(int t=0;t<4;t++){
      const float* wrow = WT + (size_t)(dc*4+t)*O + og*8;
      float4 wa = *(const float4*)wrow;
      float4 wb = *(const float4*)(wrow+4);
      #pragma unroll
      for(int jk=0;jk<8;jk++){
        float gs = ((const float*)&g4[jk])[t];
        acc[jk][0] += gs*wa.x; acc[jk][1] += gs*wa.y; acc[jk][2] += gs*wa.z; acc[jk][3] += gs*wa.w;
        acc[jk][4] += gs*wb.x; acc[jk][5] += gs*wb.y; acc[jk][6] += gs*wb.z; acc[jk][7] += gs*wb.w;
      }
    }
  }
  float tmx[8],tmn[8],tsm[8],tsq[8];
  #pragma unroll
  for(int jo=0;jo<8;jo++){
    int o = og*8+jo;
    float ct = sct[o];
    float s=0.f,q=0.f,mx=-FLT_MAX,mn=FLT_MAX;
    #pragma unroll
    for(int jk=0;jk<8;jk++){
      float h = acc[jk][jo] + ct;
      s+=h; q+=h*h; mx=fmaxf(mx,h); mn=fminf(mn,h);
    }
    tmx[jo]=mx; tmn[jo]=mn; tsm[jo]=s; tsq[jo]=q;
  }
  #pragma unroll
  for(int jo=0;jo<8;jo++){
    tmx[jo]=fmaxf(tmx[jo],__shfl_xor(tmx[jo],16)); tmx[jo]=fmaxf(tmx[jo],__shfl_xor(tmx[jo],32));
    tmn[jo]=fminf(tmn[jo],__shfl_xor(tmn[jo],16)); tmn[jo]=fminf(tmn[jo],__shfl_xor(tmn[jo],32));
    tsm[jo]+=__shfl_xor(tsm[jo],16); tsm[jo]+=__shfl_xor(tsm[jo],32);
    tsq[jo]+=__shfl_xor(tsq[jo],16); tsq[jo]+=__shfl_xor(tsq[jo],32);
  }
  if(lane<OG){
    #pragma unroll
    for(int jo=0;jo<8;jo++){
      int o = lane*8+jo;
      hmax[(size_t)bq*O+o]=tmx[jo]; hmin[(size_t)bq*O+o]=tmn[jo];
      part[(size_t)bq*2*O+o]=tsm[jo]; part[(size_t)bq*2*O+O+o]=tsq[jo];
    }
  }
}

// block-level pass1 (used by L6 / MODE2 path)
template<int C, int P, int MODE>
__device__ void pass1_body(int bq, const float* __restrict__ feats, const float* __restrict__ feats2,
                           const int* knnrow, int ci, const float* __restrict__ WT,
                           float* __restrict__ hmax, float* __restrict__ hmin,
                           float* __restrict__ part, int S,
                           const float* __restrict__ accS, const float* __restrict__ accQ,
                           const float* __restrict__ bg, const float* __restrict__ bb,
                           char* smem){
  constexpr int O   = 2*C;
  constexpr int TPB = C;
  constexpr int C4  = C/4;
  constexpr int OG  = O/8;
  constexpr int LDC = C+4;
  float* gfp = (float*)smem;            // KK*LDC
  float* cf  = gfp + KK*LDC;            // C
  float* sa  = cf + C;                  // C
  float* sbb = sa + C;                  // C
  float* sct = sbb + C;                 // O
  int tid = threadIdx.x;
  int b = bq / S;
  const float* fb = feats + (size_t)b*P*C;
  const float* fb2 = (MODE==2) ? feats2 + (size_t)b*P*C : nullptr;
  {
    float Mv = (MODE==1) ? MROWS : M0F;
    float S_=accS[tid], Q_=accQ[tid];
    float m = S_/Mv, vv = Q_/Mv - m*m; if(vv<0.f) vv=0.f;
    float a = rsqrtf(vv+EPSV)*bg[tid];
    float sh = bb[tid] - m*a;
    sa[tid]=a; sbb[tid]=sh;
    float raw;
    if(MODE==1) raw = fb[(size_t)ci*C + tid];
    else        raw = (a>=0.f) ? fb[(size_t)ci*C + tid] : fb2[(size_t)ci*C + tid];
    float cv = a*raw + sh;
    cf[tid] = cv>0.f ? cv : 0.f;
  }
  __syncthreads();
  for(int i=tid; i<KK*C4; i+=TPB){
    int k = i/C4, d4 = i - k*C4;
    size_t row = (size_t)knnrow[k]*C;
    float4 a4 = *(const float4*)&sa[d4*4];
    float4 s4 = *(const float4*)&sbb[d4*4];
    float4 c4 = *(const float4*)&cf[d4*4];
    float4 g  = ((const float4*)(fb + row))[d4];
    float4 r;
    if(MODE==2){
      float4 g2 = ((const float4*)(fb2 + row))[d4];
      float gx = (a4.x>=0.f? g.x : g2.x)*a4.x + s4.x; gx = gx>0.f?gx:0.f;
      float gy = (a4.y>=0.f? g.y : g2.y)*a4.y + s4.y; gy = gy>0.f?gy:0.f;
      float gz = (a4.z>=0.f? g.z : g2.z)*a4.z + s4.z; gz = gz>0.f?gz:0.f;
      float gw = (a4.w>=0.f? g.w : g2.w)*a4.w + s4.w; gw = gw>0.f?gw:0.f;
      r.x=gx-c4.x; r.y=gy-c4.y; r.z=gz-c4.z; r.w=gw-c4.w;
    } else {
      float gx = a4.x*g.x+s4.x; gx = gx>0.f?gx:0.f;
      float gy = a4.y*g.y+s4.y; gy = gy>0.f?gy:0.f;
      float gz = a4.z*g.z+s4.z; gz = gz>0.f?gz:0.f;
      float gw = a4.w*g.w+s4.w; gw = gw>0.f?gw:0.f;
      r.x=gx-c4.x; r.y=gy-c4.y; r.z=gz-c4.z; r.w=gw-c4.w;
    }
    *(float4*)&gfp[k*LDC + d4*4] = r;
  }
  __syncthreads();
  {
    int o2 = tid*2;
    float ct0=0.f, ct1=0.f;
    for(int c=0;c<C;c+=4){
      float4 c4 = *(const float4*)&cf[c];
      #pragma unroll
      for(int t=0;t<4;t++){
        float cv = ((const float*)&c4)[t];
        float2 wh = *(const float2*)&WT[(size_t)(C+c+t)*O + o2];
        ct0 += cv*wh.x; ct1 += cv*wh.y;
      }
    }
    sct[o2]=ct0; sct[o2+1]=ct1;
  }
  __syncthreads();
  int kg = tid / OG;
  int og = tid % OG;
  float acc[8][8];
  #pragma unroll
  for(int a=0;a<8;a++)
    #pragma unroll
    for(int bb2=0;bb2<8;bb2++) acc[a][bb2]=0.f;
  for(int dc=0; dc<C4; dc++){
    float4 g4[8];
    #pragma unroll
    for(int jk=0;jk<8;jk++) g4[jk] = *(const float4*)&gfp[(kg*8+jk)*LDC + dc*4];
    #pragma unroll
    for(int t=0;t<4;t++){
      const float* wrow = WT + (size_t)(dc*4+t)*O + og*8;
      float4 wa = *(const float4*)wrow;
      float4 wb = *(const float4*)(wrow+4);
      #pragma unroll
      for(int jk=0;jk<8;jk++){
        float gs = ((const float*)&g4[jk])[t];
        acc[jk][0] += gs*wa.x; acc[jk][1] += gs*wa.y; acc[jk][2] += gs*wa.z; acc[jk][3] += gs*wa.w;
        acc[jk][4] += gs*wb.x; acc[jk][5] += gs*wb.y; acc[jk][6] += gs*wb.z; acc[jk][7] += gs*wb.w;
      }
    }
  }
  float tmx[8],tmn[8],tsm[8],tsq[8];
  #pragma unroll
  for(int jo=0;jo<8;jo++){
    int o = og*8+jo;
    float ct = sct[o];
    float s=0.f,q=0.f,mx=-FLT_MAX,mn=FLT_MAX;
    #pragma unroll
    for(int jk=0;jk<8;jk++){
      float h = acc[jk][jo] + ct;
      s+=h; q+=h*h; mx=fmaxf(mx,h); mn=fminf(mn,h);
    }
    tmx[jo]=mx; tmn[jo]=mn; tsm[jo]=s; tsq[jo]=q;
  }
  #pragma unroll
  for(int jo=0;jo<8;jo++){
    tmx[jo]=fmaxf(tmx[jo],__shfl_xor(tmx[jo],32));
    tmn[jo]=fminf(tmn[jo],__shfl_xor(tmn[jo],32));
    tsm[jo]+=__shfl_xor(tsm[jo],32);
    tsq[jo]+=__shfl_xor(tsq[jo],32);
  }
  int wv = tid>>6;
  if((tid&63)<32){
    int og_ = tid&31;
    size_t rb = (size_t)bq*2 + wv;        // doubled row per wave; combined downstream
    #pragma unroll
    for(int jo=0;jo<8;jo++){
      int o = og_*8+jo;
      hmax[rb*O+o]=tmx[jo]; hmin[rb*O+o]=tmn[jo];
      part[rb*2*O+o]=tsm[jo]; part[rb*2*O+O+o]=tsq[jo];
    }
  }
}

// ================= kernels =================

// L1: embed1+BN1-stats (0..511) || wt (512..831). Accumulators pre-zeroed by hipMemsetAsync.
__global__ __launch_bounds__(256) void k_embed1_wt(const float* __restrict__ x, const float* __restrict__ w1,
                         float* __restrict__ coords, float* __restrict__ t1,
                         const float* __restrict__ wsg0, float* __restrict__ wt0,
                         const float* __restrict__ wsg1, float* __restrict__ wt1,
                         float* __restrict__ acc1S, float* __restrict__ acc1Q){
  if(blockIdx.x < 512) embed1_body(blockIdx.x, x, w1, coords, t1, acc1S, acc1Q);
  else wt_body((blockIdx.x-512)*256 + threadIdx.x, wsg0, wt0, wsg1, wt1);
}

// L2: embed2 + fused BN2 stats (own kernel -> t2/acc2 are prior-kernel data for mega)
__global__ __launch_bounds__(256, 1) void k_embed2(const float* __restrict__ t1, const float* __restrict__ w2,
                         const float* __restrict__ acc1S, const float* __restrict__ acc1Q,
                         const float* __restrict__ g1, const float* __restrict__ b1,
                         float* __restrict__ t2,
                         float* __restrict__ acc2S, float* __restrict__ acc2Q){
  extern __shared__ char smem[];
  __shared__ float ls[64], lq[64];
  embed2_body(blockIdx.x, t1, w2, acc1S, acc1Q, g1, b1, t2, acc2S, acc2Q, ls, lq, smem);
}

// MEGA: deadlock-free ticket queue (r4 protocol, r5 perf fixes: setprio + lane0 poll).
//   tickets [0,16):   fps0 per batch @prio3 (v4 frozen loop + release publish /32 iters)
//   tickets [16,20):  fps1 quads @prio3 (wave-local; waits prog[b]==256)
//   tickets [20,1044): pass1a quads @prio0 — 4 (b,s)-jobs/block; waits prog[b]>=s+1
#define NT_FPS0  16
#define NT_FPS1E 20
#define NT_ALL   1044
__global__ __launch_bounds__(256) void k_mega(const float* __restrict__ x,
                         int* __restrict__ fps0i, float* __restrict__ xyz0,
                         const float* __restrict__ t2,
                         const float* __restrict__ acc2S, const float* __restrict__ acc2Q,
                         const float* __restrict__ coords, const float* __restrict__ wt0,
                         float* __restrict__ hmax0, float* __restrict__ hmin0, float* __restrict__ part0,
                         const float* __restrict__ g2, const float* __restrict__ b2,
                         int* __restrict__ fps1i, float* __restrict__ xyz1,
                         int* prog, int* tck){
  extern __shared__ __align__(16) char SU[];
  __shared__ int sTk;
  int tid = threadIdx.x;
  for(;;){
    if(tid==0) sTk = atomicAdd(tck, 1);
    __syncthreads();
    int tk = sTk;
    __syncthreads();
    if(tk >= NT_ALL) return;
    if(tk < NT_FPS0){
      __builtin_amdgcn_s_setprio(3);
      fps_body<NPTS,NS0,256>(tk, x, fps0i, xyz0, SU, prog);
      __builtin_amdgcn_s_setprio(0);
    } else if(tk < NT_FPS1E){
      int wv = tid>>6;
      int b4 = (tk-NT_FPS0)*4 + wv;
      wait_ge(prog + b4, NS0);
      __builtin_amdgcn_s_setprio(3);
      fps1_wave<NS0,NS1>(b4, xyz0, fps1i, xyz1, SU + wv*4608);
      __builtin_amdgcn_s_setprio(0);
    } else {
      int q = tk - NT_FPS1E;
      int wv = tid>>6;
      int b = q & 15;
      int s = ((q>>4)<<2) + wv;
      int bq = (b<<8) + s;
      char* W = SU + wv*10112;
      int* sknn = (int*)(W + 9984);
      wait_ge(prog + b, s + 1);
      float qx = __hip_atomic_load(xyz0+(size_t)bq*3+0, __ATOMIC_RELAXED, __HIP_MEMORY_SCOPE_AGENT);
      float qy = __hip_atomic_load(xyz0+(size_t)bq*3+1, __ATOMIC_RELAXED, __HIP_MEMORY_SCOPE_AGENT);
      float qz = __hip_atomic_load(xyz0+(size_t)bq*3+2, __ATOMIC_RELAXED, __HIP_MEMORY_SCOPE_AGENT);
      int   ci = __hip_atomic_load(fps0i+bq, __ATOMIC_RELAXED, __HIP_MEMORY_SCOPE_AGENT);
      knn_compute<NPTS>(coords + (size_t)b*NPTS*3, qx, qy, qz, sknn);
      wave_sync();
      pass1a_wave(bq, t2, sknn, ci, wt0, hmax0, hmin0, part0, acc2S, acc2Q, g2, b2, W);
    }
  }
}

// L5: row-coalesced partial-sum reduce: block = 64 rows; one atomic per column
__global__ __launch_bounds__(256) void k_statsB(const float* __restrict__ part, int W,
                                                float* __restrict__ acc){
  int tid = threadIdx.x;
  int r0 = blockIdx.x*64;
  for(int c=tid; c<W; c+=256){
    float a=0.f;
    for(int r=0;r<64;r++) a += part[(size_t)(r0+r)*W + c];
    atomicAdd(acc+c, a);
  }
}

// L6: FUSED knn1+pass1b (2048 blocks x 128 thr)
__global__ __launch_bounds__(128, 2) void k_knn1_p1b(const float* __restrict__ xyz0,
                         const float* __restrict__ xyz1, const int* __restrict__ fps1,
                         const float* __restrict__ hmax0, const float* __restrict__ hmin0,
                         const float* __restrict__ wt1,
                         float* __restrict__ hmax1, float* __restrict__ hmin1, float* __restrict__ part1,
                         const float* __restrict__ accB0S, const float* __restrict__ accB0Q,
                         const float* __restrict__ gsg0, const float* __restrict__ bsg0){
  __shared__ __align__(16) char SU[19584];   // pass1b: 19456 + sknn 128
  int bq = blockIdx.x;
  int b = bq / NS1;
  int* sknn = (int*)(SU + 19456);
  if(threadIdx.x < 64){
    const float* pts = xyz0 + (size_t)b*NS0*3;
    float qx=xyz1[(size_t)bq*3], qy=xyz1[(size_t)bq*3+1], qz=xyz1[(size_t)bq*3+2];
    knn_compute<NS0>(pts, qx, qy, qz, sknn);
  }
  __syncthreads();
  pass1_body<128,NS0,2>(bq, hmax0, hmin0, sknn, fps1[bq], wt1, hmax1, hmin1, part1, NS1,
                        accB0S, accB0Q, gsg0, bsg0, SU);
}

// L8: stage-1 postmax + transpose via LDS tile; combines the doubled stat rows.
__global__ __launch_bounds__(256) void k_post1tr(const float* __restrict__ hmax, const float* __restrict__ hmin,
        const float* __restrict__ aS, const float* __restrict__ aQ,
        const float* __restrict__ g, const float* __restrict__ bb, float* __restrict__ out){
  __shared__ float ssc[64], ssh[64];
  __shared__ float tile[64][129];
  int tid = threadIdx.x;
  int blk = blockIdx.x; int b = blk>>2; int c0 = (blk&3)*64;
  if(tid<64){
    int o = c0+tid;
    float m = aS[o]/M1F, v = aQ[o]/M1F - m*m; if(v<0.f) v=0.f;
    float sc = rsqrtf(v+EPSV)*g[o];
    ssc[tid]=sc; ssh[tid]=bb[o]-m*sc;
  }
  __syncthreads();
  for(int i=tid; i<128*64; i+=256){
    int r=i>>6, ch=i&63;
    size_t rb = (size_t)(b*NS1+r)*2;
    float sc = ssc[ch];
    float va = hmax[rb*256 + c0+ch], vb = hmax[(rb+1)*256 + c0+ch];
    float wa = hmin[rb*256 + c0+ch], wb = hmin[(rb+1)*256 + c0+ch];
    float h = (sc>=0.f) ? fmaxf(va,vb) : fminf(wa,wb);
    float v = h*sc + ssh[ch];
    tile[ch][r] = v>0.f ? v : 0.f;
  }
  __syncthreads();
  for(int i=tid; i<64*128; i+=256){
    int ch=i>>7, s=i&127;
    out[(size_t)b*(256*NS1) + (size_t)(c0+ch)*NS1 + s] = tile[ch][s];
  }
}

extern "C" void kernel_launch(void* const* d_in, const int* in_sizes, int n_in,
                              void* d_out, int out_size, void* d_ws, size_t ws_size,
                              hipStream_t stream){
  const float* x    = (const float*)d_in[0];
  const float* w1   = (const float*)d_in[1];
  const float* g1   = (const float*)d_in[2];
  const float* b1   = (const float*)d_in[3];
  const float* w2   = (const float*)d_in[4];
  const float* g2   = (const float*)d_in[5];
  const float* b2   = (const float*)d_in[6];
  const float* wsg0 = (const float*)d_in[7];
  const float* gsg0 = (const float*)d_in[8];
  const float* bsg0 = (const float*)d_in[9];
  const float* wsg1 = (const float*)d_in[10];
  const float* gsg1 = (const float*)d_in[11];
  const float* bsg1 = (const float*)d_in[12];
  float* out = (float*)d_out;

  float* wsf = (float*)d_ws;
  float* coords = wsf;                    wsf += BATCH*NPTS*3;
  float* t1     = wsf;                    wsf += BATCH*NPTS*64;   // ALIASED: part1 after L2
  float* t2     = wsf;                    wsf += BATCH*NPTS*64;   // ALIASED: hmax1|hmin1 after mega
  float* acc1S=wsf; wsf+=64;  float* acc1Q=wsf; wsf+=64;          // contiguous accum+ctrl block
  float* acc2S=wsf; wsf+=64;  float* acc2Q=wsf; wsf+=64;
  float* accB0=wsf; wsf+=256;                                      // [S x128][Q x128]
  float* accB1=wsf; wsf+=512;                                      // [S x256][Q x256]
  int*   prog = (int*)wsf;                wsf += 16;               // fps0 progress per batch
  int*   tck  = (int*)wsf;                wsf += 1;                // ticket counter
  wsf += 15;                                                       // pad ctrl to 32 ints
  int*   fps0 = (int*)wsf;                wsf += BATCH*NS0;
  float* xyz0 = wsf;                      wsf += BATCH*NS0*3;
  float* hmax0= wsf;                      wsf += BATCH*NS0*128;
  float* hmin0= wsf;                      wsf += BATCH*NS0*128;
  float* part0= wsf;                      wsf += BATCH*NS0*2*128;
  int*   fps1 = (int*)wsf;                wsf += BATCH*NS1;
  float* xyz1 = wsf;                      wsf += BATCH*NS1*3;
  float* wt0  = wsf;                      wsf += 128*128;
  float* wt1  = wsf;                      wsf += 256*256;
  // aliases (t1 dead after L2; t2 dead after mega)
  float* part1 = t1;                      // (NB1*2) x 512 floats == |t1|
  float* hmax1 = t2;                      // (NB1*2) x 256
  float* hmin1 = t2 + BATCH*NS1*2*256;

  const int DYN_E2   = (4096 + 256)*4;    // embed2: fin 4096 + 4x64 params
  const int DYN_MEGA = 4*10112;           // >= fps0 25664, 4x p1a 40448, 4x fps1 18432

  // L0: zero accumulators + control block (1024 floats + 32 ints), graph-capture safe
  hipMemsetAsync(acc1S, 0, (1024+32)*sizeof(float), stream);
  // L1: embed1 + fused BN1 stats || weight transposes
  k_embed1_wt<<<dim3(832), dim3(256), 0, stream>>>(x, w1, coords, t1, wsg0, wt0, wsg1, wt1,
                                                   acc1S, acc1Q);
  // L2: embed2 + fused BN2 stats (exposed; makes t2/acc2 prior-kernel data)
  k_embed2<<<dim3(512), dim3(256), DYN_E2, stream>>>(t1, w2, acc1S, acc1Q, g1, b1,
                                                     t2, acc2S, acc2Q);
  // MEGA: fps0@prio3 || fps1@prio3 || streamed knn0+pass1a@prio0
  k_mega<<<dim3(NT_ALL), dim3(256), DYN_MEGA, stream>>>(x, fps0, xyz0,
                                                  t2, acc2S, acc2Q,
                                                  coords, wt0, hmax0, hmin0, part0, g2, b2,
                                                  fps1, xyz1, prog, tck);
  // L5: reduce part0 -> accB0
  k_statsB<<<dim3(64), dim3(256), 0, stream>>>(part0, 256, accB0);
  // L6: fused knn1+pass1b (BN0-select fused; f1 never materialized)
  k_knn1_p1b<<<dim3(BATCH*NS1), dim3(128), 0, stream>>>(xyz0, xyz1, fps1,
                                                  hmax0, hmin0, wt1,
                                                  hmax1, hmin1, part1,
                                                  accB0, accB0+128, gsg0, bsg0);
  // L7: reduce part1 -> accB1
  k_statsB<<<dim3(64), dim3(256), 0, stream>>>(part1, 512, accB1);
  // L8: postmax + transpose -> out
  k_post1tr<<<dim3(64), dim3(256), 0, stream>>>(hmax1, hmin1, accB1, accB1+256, gsg1, bsg1, out);
}

// Round 6
// 394.070 us; speedup vs baseline: 1.1216x; 1.1067x over previous
//
#include <hip/hip_runtime.h>
#include <float.h>

#define BATCH 16
#define NPTS  2048
#define NS0   256
#define NS1   128
#define KK    32
#define EPSV  1e-5f
#define MROWS 32768.0f   // BATCH*NPTS
#define M0F   131072.0f  // BATCH*NS0*KK
#define M1F   65536.0f   // BATCH*NS1*KK

// exact numpy-order squared distance: ((dx*dx + dy*dy) + dz*dz), no FMA contraction
__device__ __forceinline__ float sqdist(float ax,float ay,float az,float bx,float by,float bz){
  float dx=__fsub_rn(ax,bx), dy=__fsub_rn(ay,by), dz=__fsub_rn(az,bz);
  return __fadd_rn(__fadd_rn(__fmul_rn(dx,dx),__fmul_rn(dy,dy)),__fmul_rn(dz,dz));
}

// ---- native f32/u32 DPP ladders (cheap wave64 reduce; winner broadcast via readlane 63)
template<int CTRL,int RM>
__device__ __forceinline__ float dpp_fmax_s(float x){
  int t = __builtin_amdgcn_update_dpp((int)0xFF800000, __float_as_int(x), CTRL, RM, 0xf, false);
  return fmaxf(x, __int_as_float(t));
}
template<int CTRL,int RM>
__device__ __forceinline__ unsigned dpp_umin_s(unsigned x){
  unsigned t = (unsigned)__builtin_amdgcn_update_dpp(-1, (int)x, CTRL, RM, 0xf, false);
  return t<x ? t : x;
}
// argmax over (v,idx): max value, tie -> lowest idx (matches np.argmax first-occurrence)
// FROZEN with fps_body v4 — do not replace with packed u64 ladder (r1: +34us regression).
__device__ __forceinline__ void wave_argmax_f32(float v, unsigned idx, float& mall, int& sel){
  float m=v;
  m=dpp_fmax_s<0x111,0xf>(m); m=dpp_fmax_s<0x112,0xf>(m); m=dpp_fmax_s<0x114,0xf>(m);
  m=dpp_fmax_s<0x118,0xf>(m); m=dpp_fmax_s<0x142,0xa>(m); m=dpp_fmax_s<0x143,0xc>(m);
  mall = __int_as_float(__builtin_amdgcn_readlane(__float_as_int(m),63));
  unsigned c = (v==mall)? idx : 0xFFFFFFFFu;
  c=dpp_umin_s<0x111,0xf>(c); c=dpp_umin_s<0x112,0xf>(c); c=dpp_umin_s<0x114,0xf>(c);
  c=dpp_umin_s<0x118,0xf>(c); c=dpp_umin_s<0x142,0xa>(c); c=dpp_umin_s<0x143,0xc>(c);
  sel = (int)(unsigned)__builtin_amdgcn_readlane((int)c,63);
}

// ---- packed u64 argmin (kept: measured neutral-to-positive in KNN tournaments, r1/r2) ----
// Non-negative f32 bit patterns order as u32, so min of (bits<<32)|idx == argmin w/ lowest-idx
// ties. Bit-identical selection to the two-pass form.
template<int CTRL,int RM>
__device__ __forceinline__ unsigned long long dpp_umin64_s(unsigned long long x){
  unsigned tlo=(unsigned)__builtin_amdgcn_update_dpp(-1,(int)(unsigned)x,        CTRL,RM,0xf,false);
  unsigned thi=(unsigned)__builtin_amdgcn_update_dpp(-1,(int)(unsigned)(x>>32), CTRL,RM,0xf,false);
  unsigned long long t=((unsigned long long)thi<<32)|tlo;
  return t<x ? t : x;
}
// argmin over (v,idx): min value, tie -> lowest idx (matches stable top_k). Single ladder.
__device__ __forceinline__ int wave_argmin_f32(float v, unsigned idx){
  unsigned long long k = ((unsigned long long)__float_as_uint(v)<<32) | (unsigned long long)idx;
  k=dpp_umin64_s<0x111,0xf>(k); k=dpp_umin64_s<0x112,0xf>(k); k=dpp_umin64_s<0x114,0xf>(k);
  k=dpp_umin64_s<0x118,0xf>(k); k=dpp_umin64_s<0x142,0xa>(k); k=dpp_umin64_s<0x143,0xc>(k);
  return (int)(unsigned)__builtin_amdgcn_readlane((int)(unsigned)k,63);
}

// ================= device bodies =================

// embed1 v3: 64 points/block, LDS-staged coalesced t1 writes + FUSED BN1 stats
// (each thread has a fixed channel c=tid&63 in the write loop -> per-thread sums are per-channel)
__device__ void embed1_body(int bid, const float* __restrict__ x, const float* __restrict__ w1,
                            float* __restrict__ coords, float* __restrict__ t1,
                            float* __restrict__ accS, float* __restrict__ accQ){
  __shared__ float w[192];
  __shared__ float xs[3][64];
  __shared__ float fin[64][65];
  __shared__ float ls[64], lq[64];
  int tid = threadIdx.x;
  if (tid < 192) w[tid] = w1[tid];
  int base = bid*64;
  int b = base / NPTS, n0 = base % NPTS;
  if (tid < 192){
    int ch = tid>>6, i = tid&63;
    xs[ch][i] = x[((size_t)b*3+ch)*NPTS + n0 + i];
  } else {
    int t = tid - 192;
    ls[t]=0.f; lq[t]=0.f;
  }
  __syncthreads();
  if (tid < 64){
    coords[(size_t)(base+tid)*3+0]=xs[0][tid];
    coords[(size_t)(base+tid)*3+1]=xs[1][tid];
    coords[(size_t)(base+tid)*3+2]=xs[2][tid];
  }
  int p = tid>>2, c0 = (tid&3)<<4;
  float cx=xs[0][p], cy=xs[1][p], cz=xs[2][p];
  #pragma unroll
  for(int j=0;j<16;j++){
    int c = c0+j;
    fin[p][c] = cx*w[c*3+0] + cy*w[c*3+1] + cz*w[c*3+2];
  }
  __syncthreads();
  float s_=0.f, q_=0.f;
  for(int i=tid;i<4096;i+=256){
    int pp=i>>6, c=i&63;
    float v = fin[pp][c];
    t1[(size_t)base*64 + i] = v;
    s_+=v; q_+=v*v;
  }
  atomicAdd(&ls[tid&63], s_);
  atomicAdd(&lq[tid&63], q_);
  __syncthreads();
  if(tid<64){ atomicAdd(accS+tid, ls[tid]); atomicAdd(accQ+tid, lq[tid]); }
}

__device__ void wt_body(int gid, const float* __restrict__ w0, float* __restrict__ wt0,
                        const float* __restrict__ w1, float* __restrict__ wt1){
  if(gid < 128*128){
    int o = gid % 128, c = gid / 128;
    wt0[gid] = w0[o*128 + c];
  } else {
    int g2 = gid - 128*128;
    if(g2 >= 256*256) return;
    int o = g2 % 256, c = g2 / 256;
    wt1[g2] = w1[o*256 + c];
  }
}

// embed2 + fused BN2 stats (hidden under fps0 — free)
__device__ void embed2_body(int bid, const float* __restrict__ t1, const float* __restrict__ w2,
                            const float* __restrict__ accS, const float* __restrict__ accQ,
                            const float* __restrict__ g1, const float* __restrict__ b1,
                            float* __restrict__ t2,
                            float* __restrict__ acc2S, float* __restrict__ acc2Q,
                            float* ls, float* lq, char* smem){
  float (*fin)[64] = (float(*)[64])smem;
  float* sm = (float*)smem + 4096;
  float* sr = sm+64; float* sg = sr+64; float* sb = sg+64;
  int tid = threadIdx.x;
  if (tid<64){
    float S=accS[tid], Q=accQ[tid];
    float m = S/MROWS, v = Q/MROWS - m*m; if(v<0.f) v=0.f;
    sm[tid]=m; sr[tid]=rsqrtf(v+EPSV); sg[tid]=g1[tid]; sb[tid]=b1[tid];
    ls[tid]=0.f; lq[tid]=0.f;
  }
  __syncthreads();
  int base = bid*64;
  for(int i=tid;i<4096;i+=256){
    int p=i>>6, c=i&63;
    float v = t1[(size_t)(base+p)*64 + c];
    v = (v - sm[c])*sr[c]*sg[c] + sb[c];
    fin[p][c] = v>0.f ? v : 0.f;
  }
  __syncthreads();
  int o = tid & 63, p0 = tid>>6;
  float acc[16];
  #pragma unroll
  for(int i=0;i<16;i++) acc[i]=0.f;
  for(int cc=0; cc<64; cc+=4){
    float4 wv = *(const float4*)(w2 + o*64 + cc);
    #pragma unroll
    for(int i=0;i<16;i++){
      float4 f4 = *(const float4*)&fin[p0 + i*4][cc];
      acc[i] += f4.x*wv.x + f4.y*wv.y + f4.z*wv.z + f4.w*wv.w;
    }
  }
  float s=0.f,q=0.f;
  #pragma unroll
  for(int i=0;i<16;i++){
    float v = acc[i];
    t2[(size_t)(base+p0+i*4)*64 + o] = v;
    s+=v; q+=v*v;
  }
  atomicAdd(&ls[o], s);
  atomicAdd(&lq[o], q);
  __syncthreads();
  if(tid<64){ atomicAdd(acc2S+tid, ls[tid]); atomicAdd(acc2Q+tid, lq[tid]); }
}

// multi-wave FPS v4 (FROZEN: measured 124-127us. Do not restructure.)
// r1: packed-u64 ladder + xyz-payload combine regressed to 161us — reverted.
// r4/r5: persistent-kernel overlap (consumers streamed under this loop) net-negative
// (mega 227-229us vs sequential 196us; consumer occupancy collapsed by shared regalloc).
template<int P, int S, int T>
__device__ void fps_body(int b, const float* __restrict__ x, int* __restrict__ outIdx,
                         float* __restrict__ outXyz, char* smem){
  constexpr int PPT = P/T;
  constexpr int NW  = T/64;
  float* sx=(float*)smem; float* sy=sx+P; float* sz=sy+P;
  int* sidx=(int*)(sz+P);
  unsigned long long* rv64=(unsigned long long*)(sidx+S);
  int tid = threadIdx.x;
  const float* xb = x + (size_t)b*3*P;
  float px[PPT], py[PPT], pz[PPT], dist[PPT];
  #pragma unroll
  for(int i=0;i<PPT;i++){
    int n = i*T + tid;
    float X=xb[n], Y=xb[P+n], Z=xb[2*P+n];
    px[i]=X; py[i]=Y; pz[i]=Z; dist[i]=1e10f;
    sx[n]=X; sy[n]=Y; sz[n]=Z;
  }
  __syncthreads();
  int cur = 0;
  float cx=sx[0], cy=sy[0], cz=sz[0];
  for(int s=0;s<S;s++){
    if(tid==0) sidx[s]=cur;
    if(s==S-1) break;
    float bv=-FLT_MAX; int bi=0;
    #pragma unroll
    for(int i=0;i<PPT;i++){
      float d = sqdist(px[i],py[i],pz[i],cx,cy,cz);
      float nd = fminf(dist[i], d);
      dist[i]=nd;
      int n = i*T + tid;
      if(nd>bv){ bv=nd; bi=n; }
    }
    float mall; int sel;
    wave_argmax_f32(bv,(unsigned)bi,mall,sel);
    int sl = s & 1;
    if((tid&63)==0) rv64[sl*NW+(tid>>6)] = ((unsigned long long)__float_as_uint(mall)<<32)|(unsigned)(~sel);
    __syncthreads();
    unsigned long long wk = rv64[sl*NW];
    #pragma unroll
    for(int w=1;w<NW;w++){ unsigned long long t = rv64[sl*NW+w]; if(t>wk) wk=t; }
    cur = (int)(~(unsigned)wk);
    cx=sx[cur]; cy=sy[cur]; cz=sz[cur];
  }
  __syncthreads();
  for(int i=tid; i<S; i+=T){
    int id = sidx[i];
    outIdx[b*S+i] = id;
    outXyz[((size_t)b*S+i)*3+0] = sx[id];
    outXyz[((size_t)b*S+i)*3+1] = sy[id];
    outXyz[((size_t)b*S+i)*3+2] = sz[id];
  }
}

// single-wave FPS; float4-packed LDS points (hidden under L4 bulk)
template<int P, int S>
__device__ void fps_wave_body(int b, const float* __restrict__ pts, int* __restrict__ outIdx,
                              float* __restrict__ outXyz, char* smem){
  constexpr int PPT = P/64;
  float4* sp = (float4*)smem;
  int* sidx = (int*)(smem + P*sizeof(float4));
  int lane = threadIdx.x;
  const float* p = pts + (size_t)b*P*3;
  float px[PPT], py[PPT], pz[PPT], dist[PPT];
  #pragma unroll
  for(int i=0;i<PPT;i++){
    int n = i*64 + lane;
    float X=p[n*3], Y=p[n*3+1], Z=p[n*3+2];
    px[i]=X; py[i]=Y; pz[i]=Z; dist[i]=1e10f;
    sp[n] = make_float4(X,Y,Z,0.f);
  }
  __syncthreads();
  int cur = 0;
  float cx=sp[0].x, cy=sp[0].y, cz=sp[0].z;
  for(int s=0;s<S;s++){
    if(lane==0) sidx[s]=cur;
    if(s==S-1) break;
    float bv=-FLT_MAX; int bi=0;
    #pragma unroll
    for(int i=0;i<PPT;i++){
      float d = sqdist(px[i],py[i],pz[i],cx,cy,cz);
      float nd = fminf(dist[i], d);
      dist[i]=nd;
      int n = i*64 + lane;
      if(nd>bv){ bv=nd; bi=n; }
    }
    float mall; int sel;
    wave_argmax_f32(bv,(unsigned)bi,mall,sel);
    cur = sel;
    float4 cp = sp[cur];
    cx=cp.x; cy=cp.y; cz=cp.z;
  }
  __syncthreads();
  for(int i=lane; i<S; i+=64){
    int id = sidx[i];
    float4 cp = sp[id];
    outIdx[b*S+i] = id;
    outXyz[((size_t)b*S+i)*3+0] = cp.x;
    outXyz[((size_t)b*S+i)*3+1] = cp.y;
    outXyz[((size_t)b*S+i)*3+2] = cp.z;
  }
}

// KNN tournament v3: per-lane top-2 cache + consumed bitmask, one wave; single-ladder argmin.
// Selection bit-identical to full rescan.
template<int P>
__device__ void knn_compute(const float* __restrict__ p, float qx, float qy, float qz,
                            int* outRow){
  constexpr int E = P/64;
  int lane = threadIdx.x & 63;
  float dl[E];
  float b1=FLT_MAX, b2=FLT_MAX;
  unsigned i1=0xFFFFFFFFu, i2=0xFFFFFFFFu, consumed=0u;
  #pragma unroll
  for(int i=0;i<E;i++){
    unsigned n = i*64 + lane;
    float v = sqdist(qx,qy,qz,p[n*3],p[n*3+1],p[n*3+2]);
    dl[i] = v;
    bool lt1 = v<b1, lt2 = v<b2;
    float    nb2 = lt1 ? b1 : (lt2 ? v : b2);
    unsigned ni2 = lt1 ? i1 : (lt2 ? n : i2);
    b1 = lt1 ? v : b1; i1 = lt1 ? n : i1;
    b2 = nb2; i2 = ni2;
  }
  for(int j=0;j<KK;j++){
    int sel = wave_argmin_f32(b1, i1);
    if(lane==0) outRow[j] = sel;
    if((sel & 63) == lane){
      consumed |= 1u << (sel >> 6);
      b1 = b2; i1 = i2;
      b2 = FLT_MAX; i2 = 0xFFFFFFFFu;
      if(b1 == FLT_MAX){
        #pragma unroll
        for(int i=0;i<E;i++){
          float v = ((consumed>>i)&1u) ? FLT_MAX : dl[i];
          unsigned n = i*64 + lane;
          bool lt1 = v<b1, lt2 = v<b2;
          float    nb2 = lt1 ? b1 : (lt2 ? v : b2);
          unsigned ni2 = lt1 ? i1 : (lt2 ? n : i2);
          b1 = lt1 ? v : b1; i1 = lt1 ? n : i1;
          b2 = nb2; i2 = ni2;
        }
      }
    }
  }
}

// register-tiled outer-product GEMM with fused input transform; smem carved by caller.
// MODE 1: BN+ReLU from raw sums (pass1a, feats=t2).
// MODE 2: BN-select+ReLU over (hmax0,hmin0) (pass1b) — f1 never materialized.
template<int C, int P, int MODE>
__device__ void pass1_body(int bq, const float* __restrict__ feats, const float* __restrict__ feats2,
                           const int* knnrow, int ci, const float* __restrict__ WT,
                           float* __restrict__ hmax, float* __restrict__ hmin,
                           float* __restrict__ part, int S,
                           const float* __restrict__ accS, const float* __restrict__ accQ,
                           const float* __restrict__ bg, const float* __restrict__ bb,
                           char* smem){
  constexpr int O   = 2*C;
  constexpr int TPB = C;
  constexpr int C4  = C/4;
  constexpr int OG  = O/8;
  constexpr int LDC = C+4;
  float* gfp = (float*)smem;            // KK*LDC
  float* cf  = gfp + KK*LDC;            // C
  float* sa  = cf + C;                  // C
  float* sbb = sa + C;                  // C
  float* sct = sbb + C;                 // O
  int tid = threadIdx.x;
  int b = bq / S;
  const float* fb = feats + (size_t)b*P*C;
  const float* fb2 = (MODE==2) ? feats2 + (size_t)b*P*C : nullptr;
  {
    float Mv = (MODE==1) ? MROWS : M0F;
    float S_=accS[tid], Q_=accQ[tid];
    float m = S_/Mv, vv = Q_/Mv - m*m; if(vv<0.f) vv=0.f;
    float a = rsqrtf(vv+EPSV)*bg[tid];
    float sh = bb[tid] - m*a;
    sa[tid]=a; sbb[tid]=sh;
    float raw;
    if(MODE==1) raw = fb[(size_t)ci*C + tid];
    else        raw = (a>=0.f) ? fb[(size_t)ci*C + tid] : fb2[(size_t)ci*C + tid];
    float cv = a*raw + sh;
    cf[tid] = cv>0.f ? cv : 0.f;
  }
  __syncthreads();
  for(int i=tid; i<KK*C4; i+=TPB){
    int k = i/C4, d4 = i - k*C4;
    size_t row = (size_t)knnrow[k]*C;
    float4 a4 = *(const float4*)&sa[d4*4];
    float4 s4 = *(const float4*)&sbb[d4*4];
    float4 c4 = *(const float4*)&cf[d4*4];
    float4 g  = ((const float4*)(fb + row))[d4];
    float4 r;
    if(MODE==2){
      float4 g2 = ((const float4*)(fb2 + row))[d4];
      float gx = (a4.x>=0.f? g.x : g2.x)*a4.x + s4.x; gx = gx>0.f?gx:0.f;
      float gy = (a4.y>=0.f? g.y : g2.y)*a4.y + s4.y; gy = gy>0.f?gy:0.f;
      float gz = (a4.z>=0.f? g.z : g2.z)*a4.z + s4.z; gz = gz>0.f?gz:0.f;
      float gw = (a4.w>=0.f? g.w : g2.w)*a4.w + s4.w; gw = gw>0.f?gw:0.f;
      r.x=gx-c4.x; r.y=gy-c4.y; r.z=gz-c4.z; r.w=gw-c4.w;
    } else {
      float gx = a4.x*g.x+s4.x; gx = gx>0.f?gx:0.f;
      float gy = a4.y*g.y+s4.y; gy = gy>0.f?gy:0.f;
      float gz = a4.z*g.z+s4.z; gz = gz>0.f?gz:0.f;
      float gw = a4.w*g.w+s4.w; gw = gw>0.f?gw:0.f;
      r.x=gx-c4.x; r.y=gy-c4.y; r.z=gz-c4.z; r.w=gw-c4.w;
    }
    *(float4*)&gfp[k*LDC + d4*4] = r;
  }
  __syncthreads();
  {
    int o2 = tid*2;
    float ct0=0.f, ct1=0.f;
    for(int c=0;c<C;c+=4){
      float4 c4 = *(const float4*)&cf[c];
      #pragma unroll
      for(int t=0;t<4;t++){
        float cv = ((const float*)&c4)[t];
        float2 wh = *(const float2*)&WT[(size_t)(C+c+t)*O + o2];
        ct0 += cv*wh.x; ct1 += cv*wh.y;
      }
    }
    sct[o2]=ct0; sct[o2+1]=ct1;
  }
  __syncthreads();
  int kg = tid / OG;
  int og = tid % OG;
  float acc[8][8];
  #pragma unroll
  for(int a=0;a<8;a++)
    #pragma unroll
    for(int bb2=0;bb2<8;bb2++) acc[a][bb2]=0.f;
  for(int dc=0; dc<C4; dc++){
    float4 g4[8];
    #pragma unroll
    for(int jk=0;jk<8;jk++) g4[jk] = *(const float4*)&gfp[(kg*8+jk)*LDC + dc*4];
    #pragma unroll
    for(int t=0;t<4;t++){
      const float* wrow = WT + (size_t)(dc*4+t)*O + og*8;
      float4 wa = *(const float4*)wrow;
      float4 wb = *(const float4*)(wrow+4);
      #pragma unroll
      for(int jk=0;jk<8;jk++){
        float gs = ((const float*)&g4[jk])[t];
        acc[jk][0] += gs*wa.x; acc[jk][1] += gs*wa.y; acc[jk][2] += gs*wa.z; acc[jk][3] += gs*wa.w;
        acc[jk][4] += gs*wb.x; acc[jk][5] += gs*wb.y; acc[jk][6] += gs*wb.z; acc[jk][7] += gs*wb.w;
      }
    }
  }
  float tmx[8],tmn[8],tsm[8],tsq[8];
  #pragma unroll
  for(int jo=0;jo<8;jo++){
    int o = og*8+jo;
    float ct = sct[o];
    float s=0.f,q=0.f,mx=-FLT_MAX,mn=FLT_MAX;
    #pragma unroll
    for(int jk=0;jk<8;jk++){
      float h = acc[jk][jo] + ct;
      s+=h; q+=h*h; mx=fmaxf(mx,h); mn=fminf(mn,h);
    }
    tmx[jo]=mx; tmn[jo]=mn; tsm[jo]=s; tsq[jo]=q;
  }
  if constexpr (TPB==64){
    #pragma unroll
    for(int jo=0;jo<8;jo++){
      tmx[jo]=fmaxf(tmx[jo],__shfl_xor(tmx[jo],16)); tmx[jo]=fmaxf(tmx[jo],__shfl_xor(tmx[jo],32));
      tmn[jo]=fminf(tmn[jo],__shfl_xor(tmn[jo],16)); tmn[jo]=fminf(tmn[jo],__shfl_xor(tmn[jo],32));
      tsm[jo]+=__shfl_xor(tsm[jo],16); tsm[jo]+=__shfl_xor(tsm[jo],32);
      tsq[jo]+=__shfl_xor(tsq[jo],16); tsq[jo]+=__shfl_xor(tsq[jo],32);
    }
    if(tid<OG){
      #pragma unroll
      for(int jo=0;jo<8;jo++){
        int o = tid*8+jo;
        hmax[(size_t)bq*O+o]=tmx[jo]; hmin[(size_t)bq*O+o]=tmn[jo];
        part[(size_t)bq*2*O+o]=tsm[jo]; part[(size_t)bq*2*O+O+o]=tsq[jo];
      }
    }
  } else {
    #pragma unroll
    for(int jo=0;jo<8;jo++){
      tmx[jo]=fmaxf(tmx[jo],__shfl_xor(tmx[jo],32));
      tmn[jo]=fminf(tmn[jo],__shfl_xor(tmn[jo],32));
      tsm[jo]+=__shfl_xor(tsm[jo],32);
      tsq[jo]+=__shfl_xor(tsq[jo],32);
    }
    int wv = tid>>6;
    if((tid&63)<32){
      int og_ = tid&31;
      size_t rb = (size_t)bq*2 + wv;        // doubled row per wave; combined downstream
      #pragma unroll
      for(int jo=0;jo<8;jo++){
        int o = og_*8+jo;
        hmax[rb*O+o]=tmx[jo]; hmin[rb*O+o]=tmn[jo];
        part[rb*2*O+o]=tsm[jo]; part[rb*2*O+O+o]=tsq[jo];
      }
    }
  }
}

// ================= kernels =================

// L1: embed1+BN1-stats (0..511) || wt (512..831). Accumulators pre-zeroed by hipMemsetAsync.
__global__ __launch_bounds__(256) void k_embed1_wt(const float* __restrict__ x, const float* __restrict__ w1,
                         float* __restrict__ coords, float* __restrict__ t1,
                         const float* __restrict__ wsg0, float* __restrict__ wt0,
                         const float* __restrict__ wsg1, float* __restrict__ wt1,
                         float* __restrict__ acc1S, float* __restrict__ acc1Q){
  if(blockIdx.x < 512) embed1_body(blockIdx.x, x, w1, coords, t1, acc1S, acc1Q);
  else wt_body((blockIdx.x-512)*256 + threadIdx.x, wsg0, wt0, wsg1, wt1);
}

// L3: fps0 (16 blocks) || embed2+stats2 (512 blocks); dyn smem = union
__global__ __launch_bounds__(256, 1) void k_fps0_embed2(const float* __restrict__ x,
                         int* __restrict__ fps0, float* __restrict__ xyz0,
                         const float* __restrict__ t1, const float* __restrict__ w2,
                         const float* __restrict__ acc1S, const float* __restrict__ acc1Q,
                         const float* __restrict__ g1, const float* __restrict__ b1,
                         float* __restrict__ t2,
                         float* __restrict__ acc2S, float* __restrict__ acc2Q){
  extern __shared__ char smem[];
  __shared__ float ls[64], lq[64];
  if(blockIdx.x < BATCH) fps_body<NPTS,NS0,256>(blockIdx.x, x, fps0, xyz0, smem);
  else embed2_body(blockIdx.x-BATCH, t1, w2, acc1S, acc1Q, g1, b1, t2, acc2S, acc2Q, ls, lq, smem);
}

// L4: fps1 (blocks 0..15) || FUSED knn0+pass1a (blocks 16..4111). Static LDS union.
__global__ __launch_bounds__(64, 2) void k_fps1_p1a(const float* __restrict__ xyz0,
                         int* __restrict__ fps1, float* __restrict__ xyz1,
                         const float* __restrict__ coords, const float* __restrict__ t2,
                         const int* __restrict__ fps0, const float* __restrict__ wt0,
                         float* __restrict__ hmax0, float* __restrict__ hmin0, float* __restrict__ part0,
                         const float* __restrict__ acc2S, const float* __restrict__ acc2Q,
                         const float* __restrict__ g2, const float* __restrict__ b2){
  __shared__ __align__(16) char SU[10112];   // pass1a: 9984 + sknn 128; fps1 needs 4608
  if(blockIdx.x < BATCH){
    fps_wave_body<NS0,NS1>(blockIdx.x, xyz0, fps1, xyz1, SU);
    return;
  }
  int bq = blockIdx.x - BATCH;
  int b = bq / NS0;
  int* sknn = (int*)(SU + 9984);
  const float* pc = coords + (size_t)b*NPTS*3;
  float qx=xyz0[(size_t)bq*3], qy=xyz0[(size_t)bq*3+1], qz=xyz0[(size_t)bq*3+2];
  knn_compute<NPTS>(pc, qx, qy, qz, sknn);
  __syncthreads();
  pass1_body<64,NPTS,1>(bq, t2, nullptr, sknn, fps0[bq], wt0, hmax0, hmin0, part0, NS0,
                        acc2S, acc2Q, g2, b2, SU);
}

// L5: row-coalesced partial-sum reduce: block = 64 rows; one atomic per column
__global__ __launch_bounds__(256) void k_statsB(const float* __restrict__ part, int W,
                                                float* __restrict__ acc){
  int tid = threadIdx.x;
  int r0 = blockIdx.x*64;
  for(int c=tid; c<W; c+=256){
    float a=0.f;
    for(int r=0;r<64;r++) a += part[(size_t)(r0+r)*W + c];
    atomicAdd(acc+c, a);
  }
}

// L6: FUSED knn1+pass1b (2048 blocks x 128 thr)
__global__ __launch_bounds__(128, 2) void k_knn1_p1b(const float* __restrict__ xyz0,
                         const float* __restrict__ xyz1, const int* __restrict__ fps1,
                         const float* __restrict__ hmax0, const float* __restrict__ hmin0,
                         const float* __restrict__ wt1,
                         float* __restrict__ hmax1, float* __restrict__ hmin1, float* __restrict__ part1,
                         const float* __restrict__ accB0S, const float* __restrict__ accB0Q,
                         const float* __restrict__ gsg0, const float* __restrict__ bsg0){
  __shared__ __align__(16) char SU[19584];   // pass1b: 19456 + sknn 128
  int bq = blockIdx.x;
  int b = bq / NS1;
  int* sknn = (int*)(SU + 19456);
  if(threadIdx.x < 64){
    const float* pts = xyz0 + (size_t)b*NS0*3;
    float qx=xyz1[(size_t)bq*3], qy=xyz1[(size_t)bq*3+1], qz=xyz1[(size_t)bq*3+2];
    knn_compute<NS0>(pts, qx, qy, qz, sknn);
  }
  __syncthreads();
  pass1_body<128,NS0,2>(bq, hmax0, hmin0, sknn, fps1[bq], wt1, hmax1, hmin1, part1, NS1,
                        accB0S, accB0Q, gsg0, bsg0, SU);
}

// L8: stage-1 postmax + transpose via LDS tile; combines the doubled stat rows.
__global__ __launch_bounds__(256) void k_post1tr(const float* __restrict__ hmax, const float* __restrict__ hmin,
        const float* __restrict__ aS, const float* __restrict__ aQ,
        const float* __restrict__ g, const float* __restrict__ bb, float* __restrict__ out){
  __shared__ float ssc[64], ssh[64];
  __shared__ float tile[64][129];
  int tid = threadIdx.x;
  int blk = blockIdx.x; int b = blk>>2; int c0 = (blk&3)*64;
  if(tid<64){
    int o = c0+tid;
    float m = aS[o]/M1F, v = aQ[o]/M1F - m*m; if(v<0.f) v=0.f;
    float sc = rsqrtf(v+EPSV)*g[o];
    ssc[tid]=sc; ssh[tid]=bb[o]-m*sc;
  }
  __syncthreads();
  for(int i=tid; i<128*64; i+=256){
    int r=i>>6, ch=i&63;
    size_t rb = (size_t)(b*NS1+r)*2;
    float sc = ssc[ch];
    float va = hmax[rb*256 + c0+ch], vb = hmax[(rb+1)*256 + c0+ch];
    float wa = hmin[rb*256 + c0+ch], wb = hmin[(rb+1)*256 + c0+ch];
    float h = (sc>=0.f) ? fmaxf(va,vb) : fminf(wa,wb);
    float v = h*sc + ssh[ch];
    tile[ch][r] = v>0.f ? v : 0.f;
  }
  __syncthreads();
  for(int i=tid; i<64*128; i+=256){
    int ch=i>>7, s=i&127;
    out[(size_t)b*(256*NS1) + (size_t)(c0+ch)*NS1 + s] = tile[ch][s];
  }
}

extern "C" void kernel_launch(void* const* d_in, const int* in_sizes, int n_in,
                              void* d_out, int out_size, void* d_ws, size_t ws_size,
                              hipStream_t stream){
  const float* x    = (const float*)d_in[0];
  const float* w1   = (const float*)d_in[1];
  const float* g1   = (const float*)d_in[2];
  const float* b1   = (const float*)d_in[3];
  const float* w2   = (const float*)d_in[4];
  const float* g2   = (const float*)d_in[5];
  const float* b2   = (const float*)d_in[6];
  const float* wsg0 = (const float*)d_in[7];
  const float* gsg0 = (const float*)d_in[8];
  const float* bsg0 = (const float*)d_in[9];
  const float* wsg1 = (const float*)d_in[10];
  const float* gsg1 = (const float*)d_in[11];
  const float* bsg1 = (const float*)d_in[12];
  float* out = (float*)d_out;

  float* wsf = (float*)d_ws;
  float* coords = wsf;                    wsf += BATCH*NPTS*3;
  float* t1     = wsf;                    wsf += BATCH*NPTS*64;   // ALIASED: part1 after L3
  float* t2     = wsf;                    wsf += BATCH*NPTS*64;   // ALIASED: hmax1|hmin1 after L4
  float* acc1S=wsf; wsf+=64;  float* acc1Q=wsf; wsf+=64;          // contiguous 1024-float accum block
  float* acc2S=wsf; wsf+=64;  float* acc2Q=wsf; wsf+=64;
  float* accB0=wsf; wsf+=256;                                      // [S x128][Q x128]
  float* accB1=wsf; wsf+=512;                                      // [S x256][Q x256]
  int*   fps0 = (int*)wsf;                wsf += BATCH*NS0;
  float* xyz0 = wsf;                      wsf += BATCH*NS0*3;
  float* hmax0= wsf;                      wsf += BATCH*NS0*128;
  float* hmin0= wsf;                      wsf += BATCH*NS0*128;
  float* part0= wsf;                      wsf += BATCH*NS0*2*128;
  int*   fps1 = (int*)wsf;                wsf += BATCH*NS1;
  float* xyz1 = wsf;                      wsf += BATCH*NS1*3;
  float* wt0  = wsf;                      wsf += 128*128;
  float* wt1  = wsf;                      wsf += 256*256;
  // aliases (t1 dead after L3; t2 dead after L4)
  float* part1 = t1;                      // (NB1*2) x 512 floats == |t1|
  float* hmax1 = t2;                      // (NB1*2) x 256
  float* hmin1 = t2 + BATCH*NS1*2*256;

  const int DYN_L3 = (NPTS*3 + NS0)*4 + 2*4*8;     // fps0 union (>= embed2 17408)

  // L0: zero the contiguous 1024-float accumulator block (graph-capture safe)
  hipMemsetAsync(acc1S, 0, 1024*sizeof(float), stream);
  // L1: embed1 + fused BN1 stats || weight transposes
  k_embed1_wt<<<dim3(832), dim3(256), 0, stream>>>(x, w1, coords, t1, wsg0, wt0, wsg1, wt1,
                                                   acc1S, acc1Q);
  // L3: fps0 (FROZEN v4) || embed2 + fused BN2 stats
  k_fps0_embed2<<<dim3(BATCH+512), dim3(256), DYN_L3, stream>>>(x, fps0, xyz0,
                                                  t1, w2, acc1S, acc1Q, g1, b1, t2, acc2S, acc2Q);
  // L4: fps1 || fused knn0+pass1a
  k_fps1_p1a<<<dim3(BATCH + BATCH*NS0), dim3(64), 0, stream>>>(xyz0, fps1, xyz1,
                                                  coords, t2, fps0, wt0,
                                                  hmax0, hmin0, part0,
                                                  acc2S, acc2Q, g2, b2);
  // L5: reduce part0 -> accB0
  k_statsB<<<dim3(64), dim3(256), 0, stream>>>(part0, 256, accB0);
  // L6: fused knn1+pass1b (BN0-select fused; f1 never materialized)
  k_knn1_p1b<<<dim3(BATCH*NS1), dim3(128), 0, stream>>>(xyz0, xyz1, fps1,
                                                  hmax0, hmin0, wt1,
                                                  hmax1, hmin1, part1,
                                                  accB0, accB0+128, gsg0, bsg0);
  // L7: reduce part1 -> accB1
  k_statsB<<<dim3(64), dim3(256), 0, stream>>>(part1, 512, accB1);
  // L8: postmax + transpose -> out
  k_post1tr<<<dim3(64), dim3(256), 0, stream>>>(hmax1, hmin1, accB1, accB1+256, gsg1, bsg1, out);
}

// Round 7
// 390.507 us; speedup vs baseline: 1.1318x; 1.0091x over previous
//
#include <hip/hip_runtime.h>
#include <float.h>

#define BATCH 16
#define NPTS  2048
#define NS0   256
#define NS1   128
#define KK    32
#define EPSV  1e-5f
#define MROWS 32768.0f   // BATCH*NPTS
#define M0F   131072.0f  // BATCH*NS0*KK
#define M1F   65536.0f   // BATCH*NS1*KK

// exact numpy-order squared distance: ((dx*dx + dy*dy) + dz*dz), no FMA contraction
__device__ __forceinline__ float sqdist(float ax,float ay,float az,float bx,float by,float bz){
  float dx=__fsub_rn(ax,bx), dy=__fsub_rn(ay,by), dz=__fsub_rn(az,bz);
  return __fadd_rn(__fadd_rn(__fmul_rn(dx,dx),__fmul_rn(dy,dy)),__fmul_rn(dz,dz));
}

// ---- native f32/u32 DPP ladders (cheap wave64 reduce; winner broadcast via readlane 63)
template<int CTRL,int RM>
__device__ __forceinline__ float dpp_fmax_s(float x){
  int t = __builtin_amdgcn_update_dpp((int)0xFF800000, __float_as_int(x), CTRL, RM, 0xf, false);
  return fmaxf(x, __int_as_float(t));
}
template<int CTRL,int RM>
__device__ __forceinline__ unsigned dpp_umin_s(unsigned x){
  unsigned t = (unsigned)__builtin_amdgcn_update_dpp(-1, (int)x, CTRL, RM, 0xf, false);
  return t<x ? t : x;
}
// argmax over (v,idx): max value, tie -> lowest idx (matches np.argmax first-occurrence)
// FROZEN with fps_body v4 — do not replace with packed u64 ladder (r1: +34us regression).
__device__ __forceinline__ void wave_argmax_f32(float v, unsigned idx, float& mall, int& sel){
  float m=v;
  m=dpp_fmax_s<0x111,0xf>(m); m=dpp_fmax_s<0x112,0xf>(m); m=dpp_fmax_s<0x114,0xf>(m);
  m=dpp_fmax_s<0x118,0xf>(m); m=dpp_fmax_s<0x142,0xa>(m); m=dpp_fmax_s<0x143,0xc>(m);
  mall = __int_as_float(__builtin_amdgcn_readlane(__float_as_int(m),63));
  unsigned c = (v==mall)? idx : 0xFFFFFFFFu;
  c=dpp_umin_s<0x111,0xf>(c); c=dpp_umin_s<0x112,0xf>(c); c=dpp_umin_s<0x114,0xf>(c);
  c=dpp_umin_s<0x118,0xf>(c); c=dpp_umin_s<0x142,0xa>(c); c=dpp_umin_s<0x143,0xc>(c);
  sel = (int)(unsigned)__builtin_amdgcn_readlane((int)c,63);
}

// ---- packed u64 argmin (kept: measured neutral-to-positive in KNN tournaments, r1/r2) ----
// Non-negative f32 bit patterns order as u32, so min of (bits<<32)|idx == argmin w/ lowest-idx
// ties. Bit-identical selection to the two-pass form.
template<int CTRL,int RM>
__device__ __forceinline__ unsigned long long dpp_umin64_s(unsigned long long x){
  unsigned tlo=(unsigned)__builtin_amdgcn_update_dpp(-1,(int)(unsigned)x,        CTRL,RM,0xf,false);
  unsigned thi=(unsigned)__builtin_amdgcn_update_dpp(-1,(int)(unsigned)(x>>32), CTRL,RM,0xf,false);
  unsigned long long t=((unsigned long long)thi<<32)|tlo;
  return t<x ? t : x;
}
// argmin over (v,idx): min value, tie -> lowest idx (matches stable top_k). Single ladder.
__device__ __forceinline__ int wave_argmin_f32(float v, unsigned idx){
  unsigned long long k = ((unsigned long long)__float_as_uint(v)<<32) | (unsigned long long)idx;
  k=dpp_umin64_s<0x111,0xf>(k); k=dpp_umin64_s<0x112,0xf>(k); k=dpp_umin64_s<0x114,0xf>(k);
  k=dpp_umin64_s<0x118,0xf>(k); k=dpp_umin64_s<0x142,0xa>(k); k=dpp_umin64_s<0x143,0xc>(k);
  return (int)(unsigned)__builtin_amdgcn_readlane((int)(unsigned)k,63);
}

// ================= device bodies =================

// embed1 v3: 64 points/block, LDS-staged coalesced t1 writes + FUSED BN1 stats
// (each thread has a fixed channel c=tid&63 in the write loop -> per-thread sums are per-channel)
__device__ void embed1_body(int bid, const float* __restrict__ x, const float* __restrict__ w1,
                            float* __restrict__ coords, float* __restrict__ t1,
                            float* __restrict__ accS, float* __restrict__ accQ){
  __shared__ float w[192];
  __shared__ float xs[3][64];
  __shared__ float fin[64][65];
  __shared__ float ls[64], lq[64];
  int tid = threadIdx.x;
  if (tid < 192) w[tid] = w1[tid];
  int base = bid*64;
  int b = base / NPTS, n0 = base % NPTS;
  if (tid < 192){
    int ch = tid>>6, i = tid&63;
    xs[ch][i] = x[((size_t)b*3+ch)*NPTS + n0 + i];
  } else {
    int t = tid - 192;
    ls[t]=0.f; lq[t]=0.f;
  }
  __syncthreads();
  if (tid < 64){
    coords[(size_t)(base+tid)*3+0]=xs[0][tid];
    coords[(size_t)(base+tid)*3+1]=xs[1][tid];
    coords[(size_t)(base+tid)*3+2]=xs[2][tid];
  }
  int p = tid>>2, c0 = (tid&3)<<4;
  float cx=xs[0][p], cy=xs[1][p], cz=xs[2][p];
  #pragma unroll
  for(int j=0;j<16;j++){
    int c = c0+j;
    fin[p][c] = cx*w[c*3+0] + cy*w[c*3+1] + cz*w[c*3+2];
  }
  __syncthreads();
  float s_=0.f, q_=0.f;
  for(int i=tid;i<4096;i+=256){
    int pp=i>>6, c=i&63;
    float v = fin[pp][c];
    t1[(size_t)base*64 + i] = v;
    s_+=v; q_+=v*v;
  }
  atomicAdd(&ls[tid&63], s_);
  atomicAdd(&lq[tid&63], q_);
  __syncthreads();
  if(tid<64){ atomicAdd(accS+tid, ls[tid]); atomicAdd(accQ+tid, lq[tid]); }
}

__device__ void wt_body(int gid, const float* __restrict__ w0, float* __restrict__ wt0,
                        const float* __restrict__ w1, float* __restrict__ wt1){
  if(gid < 128*128){
    int o = gid % 128, c = gid / 128;
    wt0[gid] = w0[o*128 + c];
  } else {
    int g2 = gid - 128*128;
    if(g2 >= 256*256) return;
    int o = g2 % 256, c = g2 / 256;
    wt1[g2] = w1[o*256 + c];
  }
}

// embed2 + fused BN2 stats (hidden under fps0 — free)
__device__ void embed2_body(int bid, const float* __restrict__ t1, const float* __restrict__ w2,
                            const float* __restrict__ accS, const float* __restrict__ accQ,
                            const float* __restrict__ g1, const float* __restrict__ b1,
                            float* __restrict__ t2,
                            float* __restrict__ acc2S, float* __restrict__ acc2Q,
                            float* ls, float* lq, char* smem){
  float (*fin)[64] = (float(*)[64])smem;
  float* sm = (float*)smem + 4096;
  float* sr = sm+64; float* sg = sr+64; float* sb = sg+64;
  int tid = threadIdx.x;
  if (tid<64){
    float S=accS[tid], Q=accQ[tid];
    float m = S/MROWS, v = Q/MROWS - m*m; if(v<0.f) v=0.f;
    sm[tid]=m; sr[tid]=rsqrtf(v+EPSV); sg[tid]=g1[tid]; sb[tid]=b1[tid];
    ls[tid]=0.f; lq[tid]=0.f;
  }
  __syncthreads();
  int base = bid*64;
  for(int i=tid;i<4096;i+=256){
    int p=i>>6, c=i&63;
    float v = t1[(size_t)(base+p)*64 + c];
    v = (v - sm[c])*sr[c]*sg[c] + sb[c];
    fin[p][c] = v>0.f ? v : 0.f;
  }
  __syncthreads();
  int o = tid & 63, p0 = tid>>6;
  float acc[16];
  #pragma unroll
  for(int i=0;i<16;i++) acc[i]=0.f;
  for(int cc=0; cc<64; cc+=4){
    float4 wv = *(const float4*)(w2 + o*64 + cc);
    #pragma unroll
    for(int i=0;i<16;i++){
      float4 f4 = *(const float4*)&fin[p0 + i*4][cc];
      acc[i] += f4.x*wv.x + f4.y*wv.y + f4.z*wv.z + f4.w*wv.w;
    }
  }
  float s=0.f,q=0.f;
  #pragma unroll
  for(int i=0;i<16;i++){
    float v = acc[i];
    t2[(size_t)(base+p0+i*4)*64 + o] = v;
    s+=v; q+=v*v;
  }
  atomicAdd(&ls[o], s);
  atomicAdd(&lq[o], q);
  __syncthreads();
  if(tid<64){ atomicAdd(acc2S+tid, ls[tid]); atomicAdd(acc2Q+tid, lq[tid]); }
}

// multi-wave FPS v4 (FROZEN: measured 124-127us. Do not restructure.)
// r1: packed-u64 ladder + xyz-payload combine regressed to 161us — reverted.
// r4/r5: persistent-kernel overlap (consumers streamed under this loop) net-negative
// (mega 227-229us vs sequential 196us; consumer occupancy collapsed by shared regalloc).
template<int P, int S, int T>
__device__ void fps_body(int b, const float* __restrict__ x, int* __restrict__ outIdx,
                         float* __restrict__ outXyz, char* smem){
  constexpr int PPT = P/T;
  constexpr int NW  = T/64;
  float* sx=(float*)smem; float* sy=sx+P; float* sz=sy+P;
  int* sidx=(int*)(sz+P);
  unsigned long long* rv64=(unsigned long long*)(sidx+S);
  int tid = threadIdx.x;
  const float* xb = x + (size_t)b*3*P;
  float px[PPT], py[PPT], pz[PPT], dist[PPT];
  #pragma unroll
  for(int i=0;i<PPT;i++){
    int n = i*T + tid;
    float X=xb[n], Y=xb[P+n], Z=xb[2*P+n];
    px[i]=X; py[i]=Y; pz[i]=Z; dist[i]=1e10f;
    sx[n]=X; sy[n]=Y; sz[n]=Z;
  }
  __syncthreads();
  int cur = 0;
  float cx=sx[0], cy=sy[0], cz=sz[0];
  for(int s=0;s<S;s++){
    if(tid==0) sidx[s]=cur;
    if(s==S-1) break;
    float bv=-FLT_MAX; int bi=0;
    #pragma unroll
    for(int i=0;i<PPT;i++){
      float d = sqdist(px[i],py[i],pz[i],cx,cy,cz);
      float nd = fminf(dist[i], d);
      dist[i]=nd;
      int n = i*T + tid;
      if(nd>bv){ bv=nd; bi=n; }
    }
    float mall; int sel;
    wave_argmax_f32(bv,(unsigned)bi,mall,sel);
    int sl = s & 1;
    if((tid&63)==0) rv64[sl*NW+(tid>>6)] = ((unsigned long long)__float_as_uint(mall)<<32)|(unsigned)(~sel);
    __syncthreads();
    unsigned long long wk = rv64[sl*NW];
    #pragma unroll
    for(int w=1;w<NW;w++){ unsigned long long t = rv64[sl*NW+w]; if(t>wk) wk=t; }
    cur = (int)(~(unsigned)wk);
    cx=sx[cur]; cy=sy[cur]; cz=sz[cur];
  }
  __syncthreads();
  for(int i=tid; i<S; i+=T){
    int id = sidx[i];
    outIdx[b*S+i] = id;
    outXyz[((size_t)b*S+i)*3+0] = sx[id];
    outXyz[((size_t)b*S+i)*3+1] = sy[id];
    outXyz[((size_t)b*S+i)*3+2] = sz[id];
  }
}

// single-wave FPS; float4-packed LDS points (hidden under L4 bulk)
template<int P, int S>
__device__ void fps_wave_body(int b, const float* __restrict__ pts, int* __restrict__ outIdx,
                              float* __restrict__ outXyz, char* smem){
  constexpr int PPT = P/64;
  float4* sp = (float4*)smem;
  int* sidx = (int*)(smem + P*sizeof(float4));
  int lane = threadIdx.x;
  const float* p = pts + (size_t)b*P*3;
  float px[PPT], py[PPT], pz[PPT], dist[PPT];
  #pragma unroll
  for(int i=0;i<PPT;i++){
    int n = i*64 + lane;
    float X=p[n*3], Y=p[n*3+1], Z=p[n*3+2];
    px[i]=X; py[i]=Y; pz[i]=Z; dist[i]=1e10f;
    sp[n] = make_float4(X,Y,Z,0.f);
  }
  __syncthreads();
  int cur = 0;
  float cx=sp[0].x, cy=sp[0].y, cz=sp[0].z;
  for(int s=0;s<S;s++){
    if(lane==0) sidx[s]=cur;
    if(s==S-1) break;
    float bv=-FLT_MAX; int bi=0;
    #pragma unroll
    for(int i=0;i<PPT;i++){
      float d = sqdist(px[i],py[i],pz[i],cx,cy,cz);
      float nd = fminf(dist[i], d);
      dist[i]=nd;
      int n = i*64 + lane;
      if(nd>bv){ bv=nd; bi=n; }
    }
    float mall; int sel;
    wave_argmax_f32(bv,(unsigned)bi,mall,sel);
    cur = sel;
    float4 cp = sp[cur];
    cx=cp.x; cy=cp.y; cz=cp.z;
  }
  __syncthreads();
  for(int i=lane; i<S; i+=64){
    int id = sidx[i];
    float4 cp = sp[id];
    outIdx[b*S+i] = id;
    outXyz[((size_t)b*S+i)*3+0] = cp.x;
    outXyz[((size_t)b*S+i)*3+1] = cp.y;
    outXyz[((size_t)b*S+i)*3+2] = cp.z;
  }
}

// KNN tournament v3: per-lane top-2 cache + consumed bitmask, one wave; single-ladder argmin.
// Selection bit-identical to full rescan.
template<int P>
__device__ void knn_compute(const float* __restrict__ p, float qx, float qy, float qz,
                            int* outRow){
  constexpr int E = P/64;
  int lane = threadIdx.x & 63;
  float dl[E];
  float b1=FLT_MAX, b2=FLT_MAX;
  unsigned i1=0xFFFFFFFFu, i2=0xFFFFFFFFu, consumed=0u;
  #pragma unroll
  for(int i=0;i<E;i++){
    unsigned n = i*64 + lane;
    float v = sqdist(qx,qy,qz,p[n*3],p[n*3+1],p[n*3+2]);
    dl[i] = v;
    bool lt1 = v<b1, lt2 = v<b2;
    float    nb2 = lt1 ? b1 : (lt2 ? v : b2);
    unsigned ni2 = lt1 ? i1 : (lt2 ? n : i2);
    b1 = lt1 ? v : b1; i1 = lt1 ? n : i1;
    b2 = nb2; i2 = ni2;
  }
  for(int j=0;j<KK;j++){
    int sel = wave_argmin_f32(b1, i1);
    if(lane==0) outRow[j] = sel;
    if((sel & 63) == lane){
      consumed |= 1u << (sel >> 6);
      b1 = b2; i1 = i2;
      b2 = FLT_MAX; i2 = 0xFFFFFFFFu;
      if(b1 == FLT_MAX){
        #pragma unroll
        for(int i=0;i<E;i++){
          float v = ((consumed>>i)&1u) ? FLT_MAX : dl[i];
          unsigned n = i*64 + lane;
          bool lt1 = v<b1, lt2 = v<b2;
          float    nb2 = lt1 ? b1 : (lt2 ? v : b2);
          unsigned ni2 = lt1 ? i1 : (lt2 ? n : i2);
          b1 = lt1 ? v : b1; i1 = lt1 ? n : i1;
          b2 = nb2; i2 = ni2;
        }
      }
    }
  }
}

// register-tiled outer-product GEMM with fused input transform; smem carved by caller.
// MODE 1: BN+ReLU from raw sums (pass1a, feats=t2).
// MODE 2: BN-select+ReLU over (hmax0,hmin0) (pass1b) — f1 never materialized.
template<int C, int P, int MODE>
__device__ void pass1_body(int bq, const float* __restrict__ feats, const float* __restrict__ feats2,
                           const int* knnrow, int ci, const float* __restrict__ WT,
                           float* __restrict__ hmax, float* __restrict__ hmin,
                           float* __restrict__ part, int S,
                           const float* __restrict__ accS, const float* __restrict__ accQ,
                           const float* __restrict__ bg, const float* __restrict__ bb,
                           char* smem){
  constexpr int O   = 2*C;
  constexpr int TPB = C;
  constexpr int C4  = C/4;
  constexpr int OG  = O/8;
  constexpr int LDC = C+4;
  float* gfp = (float*)smem;            // KK*LDC
  float* cf  = gfp + KK*LDC;            // C
  float* sa  = cf + C;                  // C
  float* sbb = sa + C;                  // C
  float* sct = sbb + C;                 // O
  int tid = threadIdx.x;
  int b = bq / S;
  const float* fb = feats + (size_t)b*P*C;
  const float* fb2 = (MODE==2) ? feats2 + (size_t)b*P*C : nullptr;
  {
    float Mv = (MODE==1) ? MROWS : M0F;
    float S_=accS[tid], Q_=accQ[tid];
    float m = S_/Mv, vv = Q_/Mv - m*m; if(vv<0.f) vv=0.f;
    float a = rsqrtf(vv+EPSV)*bg[tid];
    float sh = bb[tid] - m*a;
    sa[tid]=a; sbb[tid]=sh;
    float raw;
    if(MODE==1) raw = fb[(size_t)ci*C + tid];
    else        raw = (a>=0.f) ? fb[(size_t)ci*C + tid] : fb2[(size_t)ci*C + tid];
    float cv = a*raw + sh;
    cf[tid] = cv>0.f ? cv : 0.f;
  }
  __syncthreads();
  for(int i=tid; i<KK*C4; i+=TPB){
    int k = i/C4, d4 = i - k*C4;
    size_t row = (size_t)knnrow[k]*C;
    float4 a4 = *(const float4*)&sa[d4*4];
    float4 s4 = *(const float4*)&sbb[d4*4];
    float4 c4 = *(const float4*)&cf[d4*4];
    float4 g  = ((const float4*)(fb + row))[d4];
    float4 r;
    if(MODE==2){
      float4 g2 = ((const float4*)(fb2 + row))[d4];
      float gx = (a4.x>=0.f? g.x : g2.x)*a4.x + s4.x; gx = gx>0.f?gx:0.f;
      float gy = (a4.y>=0.f? g.y : g2.y)*a4.y + s4.y; gy = gy>0.f?gy:0.f;
      float gz = (a4.z>=0.f? g.z : g2.z)*a4.z + s4.z; gz = gz>0.f?gz:0.f;
      float gw = (a4.w>=0.f? g.w : g2.w)*a4.w + s4.w; gw = gw>0.f?gw:0.f;
      r.x=gx-c4.x; r.y=gy-c4.y; r.z=gz-c4.z; r.w=gw-c4.w;
    } else {
      float gx = a4.x*g.x+s4.x; gx = gx>0.f?gx:0.f;
      float gy = a4.y*g.y+s4.y; gy = gy>0.f?gy:0.f;
      float gz = a4.z*g.z+s4.z; gz = gz>0.f?gz:0.f;
      float gw = a4.w*g.w+s4.w; gw = gw>0.f?gw:0.f;
      r.x=gx-c4.x; r.y=gy-c4.y; r.z=gz-c4.z; r.w=gw-c4.w;
    }
    *(float4*)&gfp[k*LDC + d4*4] = r;
  }
  __syncthreads();
  {
    int o2 = tid*2;
    float ct0=0.f, ct1=0.f;
    for(int c=0;c<C;c+=4){
      float4 c4 = *(const float4*)&cf[c];
      #pragma unroll
      for(int t=0;t<4;t++){
        float cv = ((const float*)&c4)[t];
        float2 wh = *(const float2*)&WT[(size_t)(C+c+t)*O + o2];
        ct0 += cv*wh.x; ct1 += cv*wh.y;
      }
    }
    sct[o2]=ct0; sct[o2+1]=ct1;
  }
  __syncthreads();
  int kg = tid / OG;
  int og = tid % OG;
  float acc[8][8];
  #pragma unroll
  for(int a=0;a<8;a++)
    #pragma unroll
    for(int bb2=0;bb2<8;bb2++) acc[a][bb2]=0.f;
  for(int dc=0; dc<C4; dc++){
    float4 g4[8];
    #pragma unroll
    for(int jk=0;jk<8;jk++) g4[jk] = *(const float4*)&gfp[(kg*8+jk)*LDC + dc*4];
    #pragma unroll
    for(int t=0;t<4;t++){
      const float* wrow = WT + (size_t)(dc*4+t)*O + og*8;
      float4 wa = *(const float4*)wrow;
      float4 wb = *(const float4*)(wrow+4);
      #pragma unroll
      for(int jk=0;jk<8;jk++){
        float gs = ((const float*)&g4[jk])[t];
        acc[jk][0] += gs*wa.x; acc[jk][1] += gs*wa.y; acc[jk][2] += gs*wa.z; acc[jk][3] += gs*wa.w;
        acc[jk][4] += gs*wb.x; acc[jk][5] += gs*wb.y; acc[jk][6] += gs*wb.z; acc[jk][7] += gs*wb.w;
      }
    }
  }
  float tmx[8],tmn[8],tsm[8],tsq[8];
  #pragma unroll
  for(int jo=0;jo<8;jo++){
    int o = og*8+jo;
    float ct = sct[o];
    float s=0.f,q=0.f,mx=-FLT_MAX,mn=FLT_MAX;
    #pragma unroll
    for(int jk=0;jk<8;jk++){
      float h = acc[jk][jo] + ct;
      s+=h; q+=h*h; mx=fmaxf(mx,h); mn=fminf(mn,h);
    }
    tmx[jo]=mx; tmn[jo]=mn; tsm[jo]=s; tsq[jo]=q;
  }
  if constexpr (TPB==64){
    #pragma unroll
    for(int jo=0;jo<8;jo++){
      tmx[jo]=fmaxf(tmx[jo],__shfl_xor(tmx[jo],16)); tmx[jo]=fmaxf(tmx[jo],__shfl_xor(tmx[jo],32));
      tmn[jo]=fminf(tmn[jo],__shfl_xor(tmn[jo],16)); tmn[jo]=fminf(tmn[jo],__shfl_xor(tmn[jo],32));
      tsm[jo]+=__shfl_xor(tsm[jo],16); tsm[jo]+=__shfl_xor(tsm[jo],32);
      tsq[jo]+=__shfl_xor(tsq[jo],16); tsq[jo]+=__shfl_xor(tsq[jo],32);
    }
    if(tid<OG){
      #pragma unroll
      for(int jo=0;jo<8;jo++){
        int o = tid*8+jo;
        hmax[(size_t)bq*O+o]=tmx[jo]; hmin[(size_t)bq*O+o]=tmn[jo];
        part[(size_t)bq*2*O+o]=tsm[jo]; part[(size_t)bq*2*O+O+o]=tsq[jo];
      }
    }
  } else {
    #pragma unroll
    for(int jo=0;jo<8;jo++){
      tmx[jo]=fmaxf(tmx[jo],__shfl_xor(tmx[jo],32));
      tmn[jo]=fminf(tmn[jo],__shfl_xor(tmn[jo],32));
      tsm[jo]+=__shfl_xor(tsm[jo],32);
      tsq[jo]+=__shfl_xor(tsq[jo],32);
    }
    int wv = tid>>6;
    if((tid&63)<32){
      int og_ = tid&31;
      size_t rb = (size_t)bq*2 + wv;        // doubled row per wave; combined downstream
      #pragma unroll
      for(int jo=0;jo<8;jo++){
        int o = og_*8+jo;
        hmax[rb*O+o]=tmx[jo]; hmin[rb*O+o]=tmn[jo];
        part[rb*2*O+o]=tsm[jo]; part[rb*2*O+O+o]=tsq[jo];
      }
    }
  }
}

// ================= kernels =================

// L1: embed1+BN1-stats (0..511) || wt (512..831). Accumulators pre-zeroed by hipMemsetAsync.
__global__ __launch_bounds__(256) void k_embed1_wt(const float* __restrict__ x, const float* __restrict__ w1,
                         float* __restrict__ coords, float* __restrict__ t1,
                         const float* __restrict__ wsg0, float* __restrict__ wt0,
                         const float* __restrict__ wsg1, float* __restrict__ wt1,
                         float* __restrict__ acc1S, float* __restrict__ acc1Q){
  if(blockIdx.x < 512) embed1_body(blockIdx.x, x, w1, coords, t1, acc1S, acc1Q);
  else wt_body((blockIdx.x-512)*256 + threadIdx.x, wsg0, wt0, wsg1, wt1);
}

// L3: fps0 (16 blocks) || embed2+stats2 (512 blocks); dyn smem = union
__global__ __launch_bounds__(256, 1) void k_fps0_embed2(const float* __restrict__ x,
                         int* __restrict__ fps0, float* __restrict__ xyz0,
                         const float* __restrict__ t1, const float* __restrict__ w2,
                         const float* __restrict__ acc1S, const float* __restrict__ acc1Q,
                         const float* __restrict__ g1, const float* __restrict__ b1,
                         float* __restrict__ t2,
                         float* __restrict__ acc2S, float* __restrict__ acc2Q){
  extern __shared__ char smem[];
  __shared__ float ls[64], lq[64];
  if(blockIdx.x < BATCH) fps_body<NPTS,NS0,256>(blockIdx.x, x, fps0, xyz0, smem);
  else embed2_body(blockIdx.x-BATCH, t1, w2, acc1S, acc1Q, g1, b1, t2, acc2S, acc2Q, ls, lq, smem);
}

// L4: fps1 (blocks 0..15) || FUSED knn0+pass1a (blocks 16..4111). Static LDS union.
// r7: launch_bounds (64,2)->(64,4): force VGPR<=128 -> 16 blocks/CU (was 8 at ~188 VGPR).
// LDS: 16 x 10112 = 158KB <= 160KB. Occupancy experiment — revert if GEMM spills.
__global__ __launch_bounds__(64, 4) void k_fps1_p1a(const float* __restrict__ xyz0,
                         int* __restrict__ fps1, float* __restrict__ xyz1,
                         const float* __restrict__ coords, const float* __restrict__ t2,
                         const int* __restrict__ fps0, const float* __restrict__ wt0,
                         float* __restrict__ hmax0, float* __restrict__ hmin0, float* __restrict__ part0,
                         const float* __restrict__ acc2S, const float* __restrict__ acc2Q,
                         const float* __restrict__ g2, const float* __restrict__ b2){
  __shared__ __align__(16) char SU[10112];   // pass1a: 9984 + sknn 128; fps1 needs 4608
  if(blockIdx.x < BATCH){
    fps_wave_body<NS0,NS1>(blockIdx.x, xyz0, fps1, xyz1, SU);
    return;
  }
  int bq = blockIdx.x - BATCH;
  int b = bq / NS0;
  int* sknn = (int*)(SU + 9984);
  const float* pc = coords + (size_t)b*NPTS*3;
  float qx=xyz0[(size_t)bq*3], qy=xyz0[(size_t)bq*3+1], qz=xyz0[(size_t)bq*3+2];
  knn_compute<NPTS>(pc, qx, qy, qz, sknn);
  __syncthreads();
  pass1_body<64,NPTS,1>(bq, t2, nullptr, sknn, fps0[bq], wt0, hmax0, hmin0, part0, NS0,
                        acc2S, acc2Q, g2, b2, SU);
}

// L5: row-coalesced partial-sum reduce: block = 64 rows; one atomic per column
__global__ __launch_bounds__(256) void k_statsB(const float* __restrict__ part, int W,
                                                float* __restrict__ acc){
  int tid = threadIdx.x;
  int r0 = blockIdx.x*64;
  for(int c=tid; c<W; c+=256){
    float a=0.f;
    for(int r=0;r<64;r++) a += part[(size_t)(r0+r)*W + c];
    atomicAdd(acc+c, a);
  }
}

// L6: FUSED knn1+pass1b (2048 blocks x 128 thr)
// r7: launch_bounds (128,2)->(128,4): force VGPR<=128 -> 8 blocks/CU (was 4 at ~188 VGPR).
// LDS: 8 x 19584 = 153KB <= 160KB. Second mountain (~115-125us inferred); revert if spills.
__global__ __launch_bounds__(128, 4) void k_knn1_p1b(const float* __restrict__ xyz0,
                         const float* __restrict__ xyz1, const int* __restrict__ fps1,
                         const float* __restrict__ hmax0, const float* __restrict__ hmin0,
                         const float* __restrict__ wt1,
                         float* __restrict__ hmax1, float* __restrict__ hmin1, float* __restrict__ part1,
                         const float* __restrict__ accB0S, const float* __restrict__ accB0Q,
                         const float* __restrict__ gsg0, const float* __restrict__ bsg0){
  __shared__ __align__(16) char SU[19584];   // pass1b: 19456 + sknn 128
  int bq = blockIdx.x;
  int b = bq / NS1;
  int* sknn = (int*)(SU + 19456);
  if(threadIdx.x < 64){
    const float* pts = xyz0 + (size_t)b*NS0*3;
    float qx=xyz1[(size_t)bq*3], qy=xyz1[(size_t)bq*3+1], qz=xyz1[(size_t)bq*3+2];
    knn_compute<NS0>(pts, qx, qy, qz, sknn);
  }
  __syncthreads();
  pass1_body<128,NS0,2>(bq, hmax0, hmin0, sknn, fps1[bq], wt1, hmax1, hmin1, part1, NS1,
                        accB0S, accB0Q, gsg0, bsg0, SU);
}

// L8: stage-1 postmax + transpose via LDS tile; combines the doubled stat rows.
__global__ __launch_bounds__(256) void k_post1tr(const float* __restrict__ hmax, const float* __restrict__ hmin,
        const float* __restrict__ aS, const float* __restrict__ aQ,
        const float* __restrict__ g, const float* __restrict__ bb, float* __restrict__ out){
  __shared__ float ssc[64], ssh[64];
  __shared__ float tile[64][129];
  int tid = threadIdx.x;
  int blk = blockIdx.x; int b = blk>>2; int c0 = (blk&3)*64;
  if(tid<64){
    int o = c0+tid;
    float m = aS[o]/M1F, v = aQ[o]/M1F - m*m; if(v<0.f) v=0.f;
    float sc = rsqrtf(v+EPSV)*g[o];
    ssc[tid]=sc; ssh[tid]=bb[o]-m*sc;
  }
  __syncthreads();
  for(int i=tid; i<128*64; i+=256){
    int r=i>>6, ch=i&63;
    size_t rb = (size_t)(b*NS1+r)*2;
    float sc = ssc[ch];
    float va = hmax[rb*256 + c0+ch], vb = hmax[(rb+1)*256 + c0+ch];
    float wa = hmin[rb*256 + c0+ch], wb = hmin[(rb+1)*256 + c0+ch];
    float h = (sc>=0.f) ? fmaxf(va,vb) : fminf(wa,wb);
    float v = h*sc + ssh[ch];
    tile[ch][r] = v>0.f ? v : 0.f;
  }
  __syncthreads();
  for(int i=tid; i<64*128; i+=256){
    int ch=i>>7, s=i&127;
    out[(size_t)b*(256*NS1) + (size_t)(c0+ch)*NS1 + s] = tile[ch][s];
  }
}

extern "C" void kernel_launch(void* const* d_in, const int* in_sizes, int n_in,
                              void* d_out, int out_size, void* d_ws, size_t ws_size,
                              hipStream_t stream){
  const float* x    = (const float*)d_in[0];
  const float* w1   = (const float*)d_in[1];
  const float* g1   = (const float*)d_in[2];
  const float* b1   = (const float*)d_in[3];
  const float* w2   = (const float*)d_in[4];
  const float* g2   = (const float*)d_in[5];
  const float* b2   = (const float*)d_in[6];
  const float* wsg0 = (const float*)d_in[7];
  const float* gsg0 = (const float*)d_in[8];
  const float* bsg0 = (const float*)d_in[9];
  const float* wsg1 = (const float*)d_in[10];
  const float* gsg1 = (const float*)d_in[11];
  const float* bsg1 = (const float*)d_in[12];
  float* out = (float*)d_out;

  float* wsf = (float*)d_ws;
  float* coords = wsf;                    wsf += BATCH*NPTS*3;
  float* t1     = wsf;                    wsf += BATCH*NPTS*64;   // ALIASED: part1 after L3
  float* t2     = wsf;                    wsf += BATCH*NPTS*64;   // ALIASED: hmax1|hmin1 after L4
  float* acc1S=wsf; wsf+=64;  float* acc1Q=wsf; wsf+=64;          // contiguous 1024-float accum block
  float* acc2S=wsf; wsf+=64;  float* acc2Q=wsf; wsf+=64;
  float* accB0=wsf; wsf+=256;                                      // [S x128][Q x128]
  float* accB1=wsf; wsf+=512;                                      // [S x256][Q x256]
  int*   fps0 = (int*)wsf;                wsf += BATCH*NS0;
  float* xyz0 = wsf;                      wsf += BATCH*NS0*3;
  float* hmax0= wsf;                      wsf += BATCH*NS0*128;
  float* hmin0= wsf;                      wsf += BATCH*NS0*128;
  float* part0= wsf;                      wsf += BATCH*NS0*2*128;
  int*   fps1 = (int*)wsf;                wsf += BATCH*NS1;
  float* xyz1 = wsf;                      wsf += BATCH*NS1*3;
  float* wt0  = wsf;                      wsf += 128*128;
  float* wt1  = wsf;                      wsf += 256*256;
  // aliases (t1 dead after L3; t2 dead after L4)
  float* part1 = t1;                      // (NB1*2) x 512 floats == |t1|
  float* hmax1 = t2;                      // (NB1*2) x 256
  float* hmin1 = t2 + BATCH*NS1*2*256;

  const int DYN_L3 = (NPTS*3 + NS0)*4 + 2*4*8;     // fps0 union (>= embed2 17408)

  // L0: zero the contiguous 1024-float accumulator block (graph-capture safe)
  hipMemsetAsync(acc1S, 0, 1024*sizeof(float), stream);
  // L1: embed1 + fused BN1 stats || weight transposes
  k_embed1_wt<<<dim3(832), dim3(256), 0, stream>>>(x, w1, coords, t1, wsg0, wt0, wsg1, wt1,
                                                   acc1S, acc1Q);
  // L3: fps0 (FROZEN v4) || embed2 + fused BN2 stats
  k_fps0_embed2<<<dim3(BATCH+512), dim3(256), DYN_L3, stream>>>(x, fps0, xyz0,
                                                  t1, w2, acc1S, acc1Q, g1, b1, t2, acc2S, acc2Q);
  // L4: fps1 || fused knn0+pass1a (r7: 4 waves/EU)
  k_fps1_p1a<<<dim3(BATCH + BATCH*NS0), dim3(64), 0, stream>>>(xyz0, fps1, xyz1,
                                                  coords, t2, fps0, wt0,
                                                  hmax0, hmin0, part0,
                                                  acc2S, acc2Q, g2, b2);
  // L5: reduce part0 -> accB0
  k_statsB<<<dim3(64), dim3(256), 0, stream>>>(part0, 256, accB0);
  // L6: fused knn1+pass1b (r7: 4 waves/EU)
  k_knn1_p1b<<<dim3(BATCH*NS1), dim3(128), 0, stream>>>(xyz0, xyz1, fps1,
                                                  hmax0, hmin0, wt1,
                                                  hmax1, hmin1, part1,
                                                  accB0, accB0+128, gsg0, bsg0);
  // L7: reduce part1 -> accB1
  k_statsB<<<dim3(64), dim3(256), 0, stream>>>(part1, 512, accB1);
  // L8: postmax + transpose -> out
  k_post1tr<<<dim3(64), dim3(256), 0, stream>>>(hmax1, hmin1, accB1, accB1+256, gsg1, bsg1, out);
}